// Round 5
// baseline (275.143 us; speedup 1.0000x reference)
//
#include <hip/hip_runtime.h>
#include <hip/hip_fp16.h>
#include <math.h>

// ---------------------------------------------------------------------------
// GCN: h1 = relu(Dinv (A+I) Dinv (x@W1) + b1); h2 = relu(Dinv (A+I) Dinv (h1@W2) + b2)
// score = (h2@aw+ab)*sigmoid(h2@mw+mb); out[g] = out_b + sum_v score*(h2@ow)
// R10 sharded bins + counting sort ->277. R12 gather_gemm fusion.
// R14: fp16 P/Q (fp32 accum) -> gathers -47us (238 total).
// BINNING SCOREBOARD (do not re-derive): R13 per-edge sharded = 58-65us FLOOR;
//   R14 x8-batched = 73; R15 two-pass aggregated = ~80. Wide+dumb wins.
// R16: gather_gemm W2-from-global + 8 blk/CU REGRESSED ~13us -> gathers are
//   THROUGHPUT-bound on random-row service (L2 miss -> L3/IF ~1.7-2 TB/s),
//   NOT latency-bound. Occupancy knobs dead. Reverted to Wl-LDS form.
// R17 (this): make the gathered array L2-RESIDENT: Q stored as 8 column
//   slices of 1.6MB (Q_s[node][8 halfs], 16B granule); gather_pool loops
//   slice-major (working set 1.6MB < 4MB/XCD L2 even with 2-slice drift).
//   4-lane engines per node, shfl_xor reduce. gather_gemm epilogue already
//   holds exactly slice cg per thread -> sliced store is free. P row-major
//   (unchanged) pending proof on pool.
// ---------------------------------------------------------------------------

#define NB 64              // nodes per bucket (bucket = v >> 6)
#define SEG 16             // counter shards per bucket
#define CAPS 80            // slots per bucket-shard; mean 40, sd 6.3
#define SLOTS (SEG * CAPS) // 1280 slots per bucket
#define BIN_BLOCKS 256

__device__ __forceinline__ void h8_set(float* a, const int4 w) {
    const __half2* h = (const __half2*)&w;
    float2 t0 = __half22float2(h[0]);
    float2 t1 = __half22float2(h[1]);
    float2 t2 = __half22float2(h[2]);
    float2 t3 = __half22float2(h[3]);
    a[0] = t0.x; a[1] = t0.y; a[2] = t1.x; a[3] = t1.y;
    a[4] = t2.x; a[5] = t2.y; a[6] = t3.x; a[7] = t3.y;
}
__device__ __forceinline__ void h8_acc(float* a, const int4 w) {
    const __half2* h = (const __half2*)&w;
    float2 t0 = __half22float2(h[0]);
    float2 t1 = __half22float2(h[1]);
    float2 t2 = __half22float2(h[2]);
    float2 t3 = __half22float2(h[3]);
    a[0] += t0.x; a[1] += t0.y; a[2] += t1.x; a[3] += t1.y;
    a[4] += t2.x; a[5] += t2.y; a[6] += t3.x; a[7] += t3.y;
}

// ---- fused: blocks [0,BIN_BLOCKS) bin edges (+ init out); rest P = x@W1 ----
__global__ __launch_bounds__(256) void gemm_bin_kernel(
    const float* __restrict__ X, const float* __restrict__ W,
    __half* __restrict__ P, int N, int K,
    const int* __restrict__ row, const int* __restrict__ col,
    int* __restrict__ bcnt, int* __restrict__ gbuf, int E,
    float* __restrict__ out, const float* __restrict__ out_b, int G) {
    __shared__ float Wl[32 * 64];    // 8 KB
    __shared__ float xs[32 * 132];   // 16.9 KB TRANSPOSED x tile [k][node]

    if (blockIdx.x < BIN_BLOCKS) {
        // R13-proven wide per-edge sharded binning (binning floor)
        int seg = blockIdx.x & (SEG - 1);
        int t = blockIdx.x * 256 + threadIdx.x;
        if (t < G) out[t] = out_b[0];
        for (int e = t; e < E; e += BIN_BLOCKS * 256) {
            int c = col[e];
            int b = c >> 6;
            // counter padded to its own 64B line: ~40 atomics/line
            int pos = atomicAdd(&bcnt[(b * SEG + seg) * 16], 1);
            if (pos < CAPS) gbuf[b * SLOTS + seg * CAPS + pos] = row[e] | ((c & 63) << 17);
        }
        return;  // uniform per-block branch; never reaches a barrier
    }

    const int tid = threadIdx.x;
    const int cg = tid & 7;        // 8 col-groups x 8 cols
    const int ng = tid >> 3;       // 32 node-groups x 4 rows = 128 nodes
    const int node0 = (blockIdx.x - BIN_BLOCKS) * 128;

    float acc[4][8];
#pragma unroll
    for (int r = 0; r < 4; r++)
#pragma unroll
        for (int j = 0; j < 8; j++) acc[r][j] = 0.0f;

    for (int k0 = 0; k0 < K; k0 += 32) {   // runtime loop: keeps VGPR bounded
        const float4* Wg = (const float4*)(W + (size_t)k0 * 64);
#pragma unroll
        for (int f = tid; f < 512; f += 256) ((float4*)Wl)[f] = Wg[f];
        {
            int rrow = tid >> 1;
            int q0 = (tid & 1) * 16;
            int node = node0 + rrow;
            const float* Xr = X + (size_t)node * K + k0 + q0;
#pragma unroll
            for (int q = 0; q < 4; q++) {
                float4 v = make_float4(0.f, 0.f, 0.f, 0.f);
                if (node < N) v = *(const float4*)(Xr + 4 * q);
                int kb = q0 + 4 * q;           // transposed store: xs[k][node]
                xs[(kb + 0) * 132 + rrow] = v.x;
                xs[(kb + 1) * 132 + rrow] = v.y;
                xs[(kb + 2) * 132 + rrow] = v.z;
                xs[(kb + 3) * 132 + rrow] = v.w;
            }
        }
        __syncthreads();
#pragma unroll
        for (int kk = 0; kk < 32; kk++) {
            float4 xv = *(const float4*)&xs[kk * 132 + ng * 4];
            const float* wr = &Wl[kk * 64 + cg * 8];
            float4 w0 = *(const float4*)(wr + 0);
            float4 w1 = *(const float4*)(wr + 4);
#pragma unroll
            for (int r = 0; r < 4; r++) {
                float xr = (r == 0) ? xv.x : (r == 1) ? xv.y : (r == 2) ? xv.z : xv.w;
                acc[r][0] = fmaf(xr, w0.x, acc[r][0]);
                acc[r][1] = fmaf(xr, w0.y, acc[r][1]);
                acc[r][2] = fmaf(xr, w0.z, acc[r][2]);
                acc[r][3] = fmaf(xr, w0.w, acc[r][3]);
                acc[r][4] = fmaf(xr, w1.x, acc[r][4]);
                acc[r][5] = fmaf(xr, w1.y, acc[r][5]);
                acc[r][6] = fmaf(xr, w1.z, acc[r][6]);
                acc[r][7] = fmaf(xr, w1.w, acc[r][7]);
            }
        }
        __syncthreads();
    }

#pragma unroll
    for (int r = 0; r < 4; r++) {
        int node = node0 + ng * 4 + r;
        if (node < N) {
            __half2 hh[4];
            hh[0] = __floats2half2_rn(acc[r][0], acc[r][1]);
            hh[1] = __floats2half2_rn(acc[r][2], acc[r][3]);
            hh[2] = __floats2half2_rn(acc[r][4], acc[r][5]);
            hh[3] = __floats2half2_rn(acc[r][6], acc[r][7]);
            ((int4*)(P + (size_t)node * 64))[cg] = *(int4*)hh;
        }
    }
}

// ---- per-bucket LDS counting sort: gbuf segments -> dense node-ordered csr
//      (4-aligned per-node regions, pre-zeroed pad), writes dinv + packed
//      startcnt, then pre-scales P' = dinv * P (fp16 rows, coalesced) ----
__global__ __launch_bounds__(256) void sort_kernel(
    const int* __restrict__ bcnt, const int* __restrict__ gbuf,
    int* __restrict__ csr, int* __restrict__ startcnt,
    float* __restrict__ dinv, __half* __restrict__ P, int N) {
    __shared__ int scnt[SEG], segoff[SEG], s_tot;
    __shared__ int ebuf[SLOTS];     // 5 KB
    __shared__ int lcnt[NB], lcur[NB];
    __shared__ float sdinv[NB];
    const int tid = threadIdx.x;
    const int b = blockIdx.x;
    const int base = b * SLOTS;

    if (tid < SEG) {
        int c = bcnt[(b * SEG + tid) * 16];
        scnt[tid] = c < CAPS ? c : CAPS;
    }
    if (tid < NB) lcnt[tid] = 0;
    __syncthreads();
    if (tid == 0) {
        int o = 0;
        for (int s = 0; s < SEG; s++) { segoff[s] = o; o += scnt[s]; }
        s_tot = o;
    }
    __syncthreads();
    for (int idx = tid; idx < SLOTS; idx += 256) {
        int seg = idx / CAPS;
        int j = idx - seg * CAPS;
        if (j < scnt[seg]) {
            int w = gbuf[base + idx];
            ebuf[segoff[seg] + j] = w;
            atomicAdd(&lcnt[(w >> 17) & 63], 1);
        }
    }
    __syncthreads();
    if (tid < NB) {
        int cntv = lcnt[tid];
        int rnd = (cntv + 3) & ~3;          // 4-aligned region for int4 loads
        int val = rnd;
#pragma unroll
        for (int off = 1; off < 64; off <<= 1) {
            int n = __shfl_up(val, off, 64);
            if (tid >= off) val += n;
        }
        int st = val - rnd;
        lcur[tid] = st;
        float d = rsqrtf(1.0f + (float)cntv);
        sdinv[tid] = d;
        int v = b * NB + tid;
        if (v < N) {
            dinv[v] = d;
            int cc = cntv < 127 ? cntv : 127;
            startcnt[v] = ((base + st) << 7) | cc;   // base+st < 2M -> fits
        }
    }
    __syncthreads();
    int tot = s_tot;
    for (int idx = tid; idx < tot; idx += 256) {
        int w = ebuf[idx];
        int vl = (w >> 17) & 63;
        int pp = atomicAdd(&lcur[vl], 1);
        csr[base + pp] = w & 131071;
    }
    // pre-scale this bucket's fp16 P rows: P'[v] = dinv[v] * P[v]
    for (int idx = tid; idx < NB * 8; idx += 256) {   // 8x16B chunks per row
        int r = idx >> 3;
        int v = b * NB + r;
        if (v < N) {
            float d = sdinv[r];
            int4* pp = (int4*)(P + (size_t)v * 64) + (idx & 7);
            int4 t = *pp;
            __half2* hp = (__half2*)&t;
#pragma unroll
            for (int q = 0; q < 4; q++) {
                float2 f = __half22float2(hp[q]);
                hp[q] = __floats2half2_rn(f.x * d, f.y * d);
            }
            *pp = t;
        }
    }
}

// ---- fused layer-1 aggregate + layer-2 GEMM (R14-proven Wl-LDS form) ----
// Phase 1: gather fp16 P' rows (8 lanes/row, int4/lane) -> fp32 -> h1 in LDS.
// Phase 2: Q' = dinv*(h1@W2) from LDS Wl; STORED SLICED: thread (cg,n0)
// holds exactly cols cg*8..cg*8+7 = slice cg -> Q_s[cg][node][8 halfs].
__global__ __launch_bounds__(256) void gather_gemm_kernel(
    const __half* __restrict__ P, const int* __restrict__ csr,
    const int* __restrict__ startcnt, const float* __restrict__ dinv,
    const float* __restrict__ b1, const float* __restrict__ W2,
    __half* __restrict__ Q, int N) {
    __shared__ float hs[64 * 65];   // 16.6 KB h1 tile
    __shared__ float Wl[64 * 64];   // 16 KB full W2
    const int tid = threadIdx.x;
    const int v0 = blockIdx.x * 64;
    const int vend = (v0 + 64 < N) ? v0 + 64 : N;
    const int p = tid & 7;          // 8 lanes per row (128B fp16 row)

    // stage W2 early; loads retire under the gather phase
    for (int f = tid; f < 1024; f += 256)
        ((float4*)Wl)[f] = ((const float4*)W2)[f];

    const float4 bb0 = ((const float4*)b1)[2 * p];
    const float4 bb1 = ((const float4*)b1)[2 * p + 1];
    for (int v = v0 + (tid >> 3); v < vend; v += 32) {
        int pack = startcnt[v];
        int st = pack >> 7;           // 4-aligned
        int c = pack & 127;
        float dv = dinv[v];
        float a[8];
        h8_set(a, ((const int4*)(P + (size_t)v * 64))[p]);   // self: P' has dv
        for (int i = 0; i < c; i += 8) {
            int4 ua = *(const int4*)(csr + st + i);      // pad slots = 0, safe
            int4 ub = *(const int4*)(csr + st + i + 4);
            int4 m0 = ((const int4*)(P + (size_t)ua.x * 64))[p];
            int4 m1 = ((const int4*)(P + (size_t)ua.y * 64))[p];
            int4 m2 = ((const int4*)(P + (size_t)ua.z * 64))[p];
            int4 m3 = ((const int4*)(P + (size_t)ua.w * 64))[p];
            int4 m4 = ((const int4*)(P + (size_t)ub.x * 64))[p];
            int4 m5 = ((const int4*)(P + (size_t)ub.y * 64))[p];
            int4 m6 = ((const int4*)(P + (size_t)ub.z * 64))[p];
            int4 m7 = ((const int4*)(P + (size_t)ub.w * 64))[p];
            h8_acc(a, m0);
            if (i + 1 < c) h8_acc(a, m1);
            if (i + 2 < c) h8_acc(a, m2);
            if (i + 3 < c) h8_acc(a, m3);
            if (i + 4 < c) h8_acc(a, m4);
            if (i + 5 < c) h8_acc(a, m5);
            if (i + 6 < c) h8_acc(a, m6);
            if (i + 7 < c) h8_acc(a, m7);
        }
        float* hd = &hs[(v - v0) * 65 + p * 8];
        hd[0] = fmaxf(fmaf(a[0], dv, bb0.x), 0.f);
        hd[1] = fmaxf(fmaf(a[1], dv, bb0.y), 0.f);
        hd[2] = fmaxf(fmaf(a[2], dv, bb0.z), 0.f);
        hd[3] = fmaxf(fmaf(a[3], dv, bb0.w), 0.f);
        hd[4] = fmaxf(fmaf(a[4], dv, bb1.x), 0.f);
        hd[5] = fmaxf(fmaf(a[5], dv, bb1.y), 0.f);
        hd[6] = fmaxf(fmaf(a[6], dv, bb1.z), 0.f);
        hd[7] = fmaxf(fmaf(a[7], dv, bb1.w), 0.f);
    }
    __syncthreads();

    // Phase 2: Q'[v] = dinv * (hs @ W2); 2 rows x 8 cols per thread
    const int cg = tid & 7;
    const int n0 = tid >> 3;       // 0..31, 2 rows each
    float acc2[2][8];
#pragma unroll
    for (int r = 0; r < 2; r++)
#pragma unroll
        for (int j = 0; j < 8; j++) acc2[r][j] = 0.0f;
    for (int kk = 0; kk < 64; kk++) {     // RUNTIME loop (R6/R8 lesson)
        float x0 = hs[(n0 * 2 + 0) * 65 + kk];
        float x1 = hs[(n0 * 2 + 1) * 65 + kk];
        const float* wr = &Wl[kk * 64 + cg * 8];
        float4 w0 = *(const float4*)(wr + 0);
        float4 w1 = *(const float4*)(wr + 4);
        acc2[0][0] = fmaf(x0, w0.x, acc2[0][0]);
        acc2[0][1] = fmaf(x0, w0.y, acc2[0][1]);
        acc2[0][2] = fmaf(x0, w0.z, acc2[0][2]);
        acc2[0][3] = fmaf(x0, w0.w, acc2[0][3]);
        acc2[0][4] = fmaf(x0, w1.x, acc2[0][4]);
        acc2[0][5] = fmaf(x0, w1.y, acc2[0][5]);
        acc2[0][6] = fmaf(x0, w1.z, acc2[0][6]);
        acc2[0][7] = fmaf(x0, w1.w, acc2[0][7]);
        acc2[1][0] = fmaf(x1, w0.x, acc2[1][0]);
        acc2[1][1] = fmaf(x1, w0.y, acc2[1][1]);
        acc2[1][2] = fmaf(x1, w0.z, acc2[1][2]);
        acc2[1][3] = fmaf(x1, w0.w, acc2[1][3]);
        acc2[1][4] = fmaf(x1, w1.x, acc2[1][4]);
        acc2[1][5] = fmaf(x1, w1.y, acc2[1][5]);
        acc2[1][6] = fmaf(x1, w1.z, acc2[1][6]);
        acc2[1][7] = fmaf(x1, w1.w, acc2[1][7]);
    }
#pragma unroll
    for (int r = 0; r < 2; r++) {
        int node = v0 + n0 * 2 + r;
        if (node < N) {
            float d = dinv[node];
            __half2 hh[4];
            hh[0] = __floats2half2_rn(acc2[r][0] * d, acc2[r][1] * d);
            hh[1] = __floats2half2_rn(acc2[r][2] * d, acc2[r][3] * d);
            hh[2] = __floats2half2_rn(acc2[r][4] * d, acc2[r][5] * d);
            hh[3] = __floats2half2_rn(acc2[r][6] * d, acc2[r][7] * d);
            // SLICED store: slice cg, 16B per node
            *(int4*)(Q + (size_t)cg * N * 8 + (size_t)node * 8) = *(int4*)hh;
        }
    }
}

// ---- layer-2 aggregate (SLICE-MAJOR, L2-resident) + attn pool + projection ----
// Q is 8 slices of [N][8 halfs] (1.6MB each). Phase A: for each slice,
// 4-lane engine per node gathers neighbors' 16B slice rows (L2-hit after
// warmup), shfl_xor reduce, relu(dv*sum+b) -> h2 LDS tile. Phase B: scores.
#define GP_NODES 64
__global__ __launch_bounds__(256) void gather_pool_kernel(
    const __half* __restrict__ Q, const int* __restrict__ csr,
    const int* __restrict__ startcnt, const float* __restrict__ dinv,
    const float* __restrict__ bias, const int* __restrict__ batch,
    const float* __restrict__ attn_w, const float* __restrict__ attn_b,
    const float* __restrict__ mask_w, const float* __restrict__ mask_b,
    const float* __restrict__ out_w, float* __restrict__ out, int N) {
    __shared__ float h2s[64 * 65];  // 16.6 KB h2 tile
    __shared__ float pacc[2048];
    __shared__ int s_gmin, s_span;
    const int tid = threadIdx.x;
    const int v0 = blockIdx.x * GP_NODES;
    const int vend = (v0 + GP_NODES < N) ? v0 + GP_NODES : N;
    if (tid == 0) {
        int gmin = batch[v0];
        s_gmin = gmin;
        s_span = batch[vend - 1] - gmin + 1;
    }
    __syncthreads();
    const int gmin = s_gmin, span = s_span;
    for (int i = tid; i < span; i += 256) pacc[i] = 0.f;

    // ---- phase A: slice-major h2 accumulation ----
    const int vi = tid >> 2;        // engine = node index 0..63
    const int j = tid & 3;          // lane within 4-lane engine
    const int v = v0 + vi;
    const bool alive = v < N;
    int st = 0, c = 0;
    float dv = 0.f;
    if (alive) {
        int pack = startcnt[v];
        st = pack >> 7;
        c = pack & 127;
        dv = dinv[v];
    }
    for (int s = 0; s < 8; s++) {
        const __half* Qs = Q + (size_t)s * N * 8;
        float a[8] = {0.f, 0.f, 0.f, 0.f, 0.f, 0.f, 0.f, 0.f};
        if (alive) {
            if (j == 0) h8_acc(a, *(const int4*)(Qs + (size_t)v * 8));  // self
            for (int i = j; i < c; i += 4) {
                int u = csr[st + i];
                h8_acc(a, *(const int4*)(Qs + (size_t)u * 8));
            }
        }
#pragma unroll
        for (int k = 0; k < 8; k++) {   // 4-lane aligned butterfly
            a[k] += __shfl_xor(a[k], 1, 64);
            a[k] += __shfl_xor(a[k], 2, 64);
        }
        if (alive && j == 0) {
            float4 bb0 = ((const float4*)bias)[2 * s];
            float4 bb1 = ((const float4*)bias)[2 * s + 1];
            float* hd = &h2s[vi * 65 + s * 8];
            hd[0] = fmaxf(fmaf(a[0], dv, bb0.x), 0.f);
            hd[1] = fmaxf(fmaf(a[1], dv, bb0.y), 0.f);
            hd[2] = fmaxf(fmaf(a[2], dv, bb0.z), 0.f);
            hd[3] = fmaxf(fmaf(a[3], dv, bb0.w), 0.f);
            hd[4] = fmaxf(fmaf(a[4], dv, bb1.x), 0.f);
            hd[5] = fmaxf(fmaf(a[5], dv, bb1.y), 0.f);
            hd[6] = fmaxf(fmaf(a[6], dv, bb1.z), 0.f);
            hd[7] = fmaxf(fmaf(a[7], dv, bb1.w), 0.f);
        }
    }
    __syncthreads();

    // ---- phase B: scores + sigmoid-masked pooled projection ----
    const int p = tid & 7;
    const int g = tid >> 3;         // 32 groups of 8 lanes
    const float4 wa0 = ((const float4*)attn_w)[2 * p], wa1 = ((const float4*)attn_w)[2 * p + 1];
    const float4 wm0 = ((const float4*)mask_w)[2 * p], wm1 = ((const float4*)mask_w)[2 * p + 1];
    const float4 wo0 = ((const float4*)out_w)[2 * p],  wo1 = ((const float4*)out_w)[2 * p + 1];
    const float ab = attn_b[0], mb = mask_b[0];

    for (int vv = g; vv < GP_NODES; vv += 32) {
        const float* hd = &h2s[vv * 65 + p * 8];
        float h0 = hd[0], h1v = hd[1], h2v = hd[2], h3 = hd[3];
        float h4 = hd[4], h5 = hd[5], h6 = hd[6], h7 = hd[7];
        float pa = h0 * wa0.x + h1v * wa0.y + h2v * wa0.z + h3 * wa0.w
                 + h4 * wa1.x + h5 * wa1.y + h6 * wa1.z + h7 * wa1.w;
        float pm = h0 * wm0.x + h1v * wm0.y + h2v * wm0.z + h3 * wm0.w
                 + h4 * wm1.x + h5 * wm1.y + h6 * wm1.z + h7 * wm1.w;
        float po = h0 * wo0.x + h1v * wo0.y + h2v * wo0.z + h3 * wo0.w
                 + h4 * wo1.x + h5 * wo1.y + h6 * wo1.z + h7 * wo1.w;
#pragma unroll
        for (int off = 1; off < 8; off <<= 1) {   // 8-lane aligned groups
            pa += __shfl_xor(pa, off, 64);
            pm += __shfl_xor(pm, off, 64);
            po += __shfl_xor(po, off, 64);
        }
        int node = v0 + vv;
        if (p == 0 && node < N) {
            float cc = (pa + ab) * (1.0f / (1.0f + expf(-(pm + mb)))) * po;
            atomicAdd(&pacc[batch[node] - gmin], cc);
        }
    }
    __syncthreads();
    for (int i = tid; i < span; i += 256) {
        float val = pacc[i];
        if (val != 0.f) atomicAdd(&out[gmin + i], val);
    }
}

extern "C" void kernel_launch(void* const* d_in, const int* in_sizes, int n_in,
                              void* d_out, int out_size, void* d_ws, size_t ws_size,
                              hipStream_t stream) {
    const float* x      = (const float*)d_in[0];
    const int*   edge   = (const int*)d_in[1];
    const int*   batch  = (const int*)d_in[2];
    const float* W1     = (const float*)d_in[3];
    const float* b1     = (const float*)d_in[4];
    const float* W2     = (const float*)d_in[5];
    const float* b2     = (const float*)d_in[6];
    const float* attn_w = (const float*)d_in[7];
    const float* attn_b = (const float*)d_in[8];
    const float* mask_w = (const float*)d_in[9];
    const float* mask_b = (const float*)d_in[10];
    const float* out_w  = (const float*)d_in[11];
    const float* out_b  = (const float*)d_in[12];
    float* out = (float*)d_out;

    const int N  = in_sizes[2];
    const int E  = in_sizes[1] / 2;
    const int K1 = in_sizes[0] / N;   // 128
    const int H  = in_sizes[4];       // 64
    const int G  = out_size;          // 2048
    const int* row = edge;            // edge_index[0] = sources
    const int* col = edge + E;        // edge_index[1] = targets

    const int NBUCK = (N + NB - 1) / NB;   // 1563

    // workspace: bcnt 1.6MB + gbuf 8MB + csr 8MB + startcnt/dinv 0.8MB
    //            + P/Q 2x12.8MB (fp16) ~= 44MB
    char* ws = (char*)d_ws;
    auto align256 = [](size_t s) { return (s + 255) / 256 * 256; };
    int*    bcnt     = (int*)ws;    ws += align256((size_t)NBUCK * SEG * 16 * 4);
    int*    gbuf     = (int*)ws;    ws += align256((size_t)NBUCK * SLOTS * 4);
    int*    csr      = (int*)ws;    ws += align256((size_t)NBUCK * SLOTS * 4);
    int*    startcnt = (int*)ws;    ws += align256((size_t)N * 4);
    float*  dinv     = (float*)ws;  ws += align256((size_t)N * 4);
    __half* P        = (__half*)ws; ws += align256((size_t)N * H * 2);
    __half* Q        = (__half*)ws;   // 8 slices of [N][8 halfs]

    const int gblocks = (N + 127) / 128;

    hipMemsetAsync(bcnt, 0, (size_t)NBUCK * SEG * 16 * 4, stream);
    hipMemsetAsync(csr, 0, (size_t)NBUCK * SLOTS * 4, stream);  // 0-pad for int4 reads

    // fused: sharded per-edge binning (+out init) || P = x@W1 (fp16 out)
    gemm_bin_kernel<<<BIN_BLOCKS + gblocks, 256, 0, stream>>>(
        x, W1, P, N, K1, row, col, bcnt, gbuf, E, out, out_b, G);

    // per-bucket counting sort -> dense 4-aligned csr + startcnt + dinv
    // + pre-scale P' = dinv * P (bucket-local, coalesced, fp16)
    sort_kernel<<<NBUCK, 256, 0, stream>>>(bcnt, gbuf, csr, startcnt, dinv, P, N);

    // fused layer-1 aggregate (h1 -> LDS) + layer-2 GEMM: Q' sliced fp16
    gather_gemm_kernel<<<NBUCK, 256, 0, stream>>>(
        P, csr, startcnt, dinv, b1, W2, Q, N);

    // layer-2 slice-major aggregate + attention pool + projection
    gather_pool_kernel<<<NBUCK, 256, 0, stream>>>(
        Q, csr, startcnt, dinv, b2, batch, attn_w, attn_b, mask_w, mask_b, out_w, out, N);
}

// Round 6
// 239.188 us; speedup vs baseline: 1.1503x; 1.1503x over previous
//
#include <hip/hip_runtime.h>
#include <hip/hip_fp16.h>
#include <math.h>

// ---------------------------------------------------------------------------
// GCN: h1 = relu(Dinv (A+I) Dinv (x@W1) + b1); h2 = relu(Dinv (A+I) Dinv (h1@W2) + b2)
// score = (h2@aw+ab)*sigmoid(h2@mw+mb); out[g] = out_b + sum_v score*(h2@ow)
// R10 sharded bins + counting sort ->277. R12 gather_gemm fusion.
// R14: fp16 P/Q (fp32 accum) -> gathers -47us (238 total).
// BINNING SCOREBOARD (do not re-derive): R13 per-edge sharded = 58us FLOOR;
//   R14 x8-batched = 73; R15 two-pass aggregated = ~80 (64-blk tail). Wide wins.
// R16: gather_gemm W2-from-global + 8 blk/CU REGRESSED ~13us -> gathers
//   throughput-bound on random-row service, NOT latency-bound. Wl-LDS is right.
// R17: slice-major Q (16B granule) REGRESSED: FETCH 66MB (line-granule
//   overfetch, L2/L3 thrash -> HBM). LESSON: 128B full-row = optimal gather
//   granule; gather-array layout experiments CLOSED.
// R18 (this): pure best-known recombination: R13 binning + fp16 GEMM store
//   (58us) + R14 sort + R14 gather_gemm (Wl LDS, row-major Q) + R14
//   gather_pool. ONE lever: BIN_BLOCKS 256->512 (post-GEMM-drain occupancy
//   1->2 waves/SIMD for the atomic chain; shard stats unchanged).
// ---------------------------------------------------------------------------

#define NB 64              // nodes per bucket (bucket = v >> 6)
#define SEG 16             // counter shards per bucket
#define CAPS 80            // slots per bucket-shard; mean 40, sd 6.3
#define SLOTS (SEG * CAPS) // 1280 slots per bucket
#define BIN_BLOCKS 512

__device__ __forceinline__ void h8_set(float* a, const int4 w) {
    const __half2* h = (const __half2*)&w;
    float2 t0 = __half22float2(h[0]);
    float2 t1 = __half22float2(h[1]);
    float2 t2 = __half22float2(h[2]);
    float2 t3 = __half22float2(h[3]);
    a[0] = t0.x; a[1] = t0.y; a[2] = t1.x; a[3] = t1.y;
    a[4] = t2.x; a[5] = t2.y; a[6] = t3.x; a[7] = t3.y;
}
__device__ __forceinline__ void h8_acc(float* a, const int4 w) {
    const __half2* h = (const __half2*)&w;
    float2 t0 = __half22float2(h[0]);
    float2 t1 = __half22float2(h[1]);
    float2 t2 = __half22float2(h[2]);
    float2 t3 = __half22float2(h[3]);
    a[0] += t0.x; a[1] += t0.y; a[2] += t1.x; a[3] += t1.y;
    a[4] += t2.x; a[5] += t2.y; a[6] += t3.x; a[7] += t3.y;
}

// ---- fused: blocks [0,BIN_BLOCKS) bin edges (+ init out); rest P = x@W1 ----
__global__ __launch_bounds__(256) void gemm_bin_kernel(
    const float* __restrict__ X, const float* __restrict__ W,
    __half* __restrict__ P, int N, int K,
    const int* __restrict__ row, const int* __restrict__ col,
    int* __restrict__ bcnt, int* __restrict__ gbuf, int E,
    float* __restrict__ out, const float* __restrict__ out_b, int G) {
    __shared__ float Wl[32 * 64];    // 8 KB
    __shared__ float xs[32 * 132];   // 16.9 KB TRANSPOSED x tile [k][node]

    if (blockIdx.x < BIN_BLOCKS) {
        // R13-proven wide per-edge sharded binning (binning floor)
        int seg = blockIdx.x & (SEG - 1);
        int t = blockIdx.x * 256 + threadIdx.x;
        if (t < G) out[t] = out_b[0];
        for (int e = t; e < E; e += BIN_BLOCKS * 256) {
            int c = col[e];
            int b = c >> 6;
            // counter padded to its own 64B line: ~40 atomics/line
            int pos = atomicAdd(&bcnt[(b * SEG + seg) * 16], 1);
            if (pos < CAPS) gbuf[b * SLOTS + seg * CAPS + pos] = row[e] | ((c & 63) << 17);
        }
        return;  // uniform per-block branch; never reaches a barrier
    }

    const int tid = threadIdx.x;
    const int cg = tid & 7;        // 8 col-groups x 8 cols
    const int ng = tid >> 3;       // 32 node-groups x 4 rows = 128 nodes
    const int node0 = (blockIdx.x - BIN_BLOCKS) * 128;

    float acc[4][8];
#pragma unroll
    for (int r = 0; r < 4; r++)
#pragma unroll
        for (int j = 0; j < 8; j++) acc[r][j] = 0.0f;

    for (int k0 = 0; k0 < K; k0 += 32) {   // runtime loop: keeps VGPR bounded
        const float4* Wg = (const float4*)(W + (size_t)k0 * 64);
#pragma unroll
        for (int f = tid; f < 512; f += 256) ((float4*)Wl)[f] = Wg[f];
        {
            int rrow = tid >> 1;
            int q0 = (tid & 1) * 16;
            int node = node0 + rrow;
            const float* Xr = X + (size_t)node * K + k0 + q0;
#pragma unroll
            for (int q = 0; q < 4; q++) {
                float4 v = make_float4(0.f, 0.f, 0.f, 0.f);
                if (node < N) v = *(const float4*)(Xr + 4 * q);
                int kb = q0 + 4 * q;           // transposed store: xs[k][node]
                xs[(kb + 0) * 132 + rrow] = v.x;
                xs[(kb + 1) * 132 + rrow] = v.y;
                xs[(kb + 2) * 132 + rrow] = v.z;
                xs[(kb + 3) * 132 + rrow] = v.w;
            }
        }
        __syncthreads();
#pragma unroll
        for (int kk = 0; kk < 32; kk++) {
            float4 xv = *(const float4*)&xs[kk * 132 + ng * 4];
            const float* wr = &Wl[kk * 64 + cg * 8];
            float4 w0 = *(const float4*)(wr + 0);
            float4 w1 = *(const float4*)(wr + 4);
#pragma unroll
            for (int r = 0; r < 4; r++) {
                float xr = (r == 0) ? xv.x : (r == 1) ? xv.y : (r == 2) ? xv.z : xv.w;
                acc[r][0] = fmaf(xr, w0.x, acc[r][0]);
                acc[r][1] = fmaf(xr, w0.y, acc[r][1]);
                acc[r][2] = fmaf(xr, w0.z, acc[r][2]);
                acc[r][3] = fmaf(xr, w0.w, acc[r][3]);
                acc[r][4] = fmaf(xr, w1.x, acc[r][4]);
                acc[r][5] = fmaf(xr, w1.y, acc[r][5]);
                acc[r][6] = fmaf(xr, w1.z, acc[r][6]);
                acc[r][7] = fmaf(xr, w1.w, acc[r][7]);
            }
        }
        __syncthreads();
    }

#pragma unroll
    for (int r = 0; r < 4; r++) {
        int node = node0 + ng * 4 + r;
        if (node < N) {
            __half2 hh[4];
            hh[0] = __floats2half2_rn(acc[r][0], acc[r][1]);
            hh[1] = __floats2half2_rn(acc[r][2], acc[r][3]);
            hh[2] = __floats2half2_rn(acc[r][4], acc[r][5]);
            hh[3] = __floats2half2_rn(acc[r][6], acc[r][7]);
            ((int4*)(P + (size_t)node * 64))[cg] = *(int4*)hh;
        }
    }
}

// ---- per-bucket LDS counting sort: gbuf segments -> dense node-ordered csr
//      (4-aligned per-node regions, pre-zeroed pad), writes dinv + packed
//      startcnt, then pre-scales P' = dinv * P (fp16 rows, coalesced) ----
__global__ __launch_bounds__(256) void sort_kernel(
    const int* __restrict__ bcnt, const int* __restrict__ gbuf,
    int* __restrict__ csr, int* __restrict__ startcnt,
    float* __restrict__ dinv, __half* __restrict__ P, int N) {
    __shared__ int scnt[SEG], segoff[SEG], s_tot;
    __shared__ int ebuf[SLOTS];     // 5 KB
    __shared__ int lcnt[NB], lcur[NB];
    __shared__ float sdinv[NB];
    const int tid = threadIdx.x;
    const int b = blockIdx.x;
    const int base = b * SLOTS;

    if (tid < SEG) {
        int c = bcnt[(b * SEG + tid) * 16];
        scnt[tid] = c < CAPS ? c : CAPS;
    }
    if (tid < NB) lcnt[tid] = 0;
    __syncthreads();
    if (tid == 0) {
        int o = 0;
        for (int s = 0; s < SEG; s++) { segoff[s] = o; o += scnt[s]; }
        s_tot = o;
    }
    __syncthreads();
    for (int idx = tid; idx < SLOTS; idx += 256) {
        int seg = idx / CAPS;
        int j = idx - seg * CAPS;
        if (j < scnt[seg]) {
            int w = gbuf[base + idx];
            ebuf[segoff[seg] + j] = w;
            atomicAdd(&lcnt[(w >> 17) & 63], 1);
        }
    }
    __syncthreads();
    if (tid < NB) {
        int cntv = lcnt[tid];
        int rnd = (cntv + 3) & ~3;          // 4-aligned region for int4 loads
        int val = rnd;
#pragma unroll
        for (int off = 1; off < 64; off <<= 1) {
            int n = __shfl_up(val, off, 64);
            if (tid >= off) val += n;
        }
        int st = val - rnd;
        lcur[tid] = st;
        float d = rsqrtf(1.0f + (float)cntv);
        sdinv[tid] = d;
        int v = b * NB + tid;
        if (v < N) {
            dinv[v] = d;
            int cc = cntv < 127 ? cntv : 127;
            startcnt[v] = ((base + st) << 7) | cc;   // base+st < 2M -> fits
        }
    }
    __syncthreads();
    int tot = s_tot;
    for (int idx = tid; idx < tot; idx += 256) {
        int w = ebuf[idx];
        int vl = (w >> 17) & 63;
        int pp = atomicAdd(&lcur[vl], 1);
        csr[base + pp] = w & 131071;
    }
    // pre-scale this bucket's fp16 P rows: P'[v] = dinv[v] * P[v]
    for (int idx = tid; idx < NB * 8; idx += 256) {   // 8x16B chunks per row
        int r = idx >> 3;
        int v = b * NB + r;
        if (v < N) {
            float d = sdinv[r];
            int4* pp = (int4*)(P + (size_t)v * 64) + (idx & 7);
            int4 t = *pp;
            __half2* hp = (__half2*)&t;
#pragma unroll
            for (int q = 0; q < 4; q++) {
                float2 f = __half22float2(hp[q]);
                hp[q] = __floats2half2_rn(f.x * d, f.y * d);
            }
            *pp = t;
        }
    }
}

// ---- fused layer-1 aggregate + layer-2 GEMM (R14-proven form) ----
// Phase 1: gather fp16 P' rows (8 lanes/row, int4/lane) -> fp32 -> h1 in LDS.
// Phase 2: Q' = dinv*(h1@W2) from LDS Wl; 2x8 register tile, RUNTIME kk-loop.
__global__ __launch_bounds__(256) void gather_gemm_kernel(
    const __half* __restrict__ P, const int* __restrict__ csr,
    const int* __restrict__ startcnt, const float* __restrict__ dinv,
    const float* __restrict__ b1, const float* __restrict__ W2,
    __half* __restrict__ Q, int N) {
    __shared__ float hs[64 * 65];   // 16.6 KB h1 tile
    __shared__ float Wl[64 * 64];   // 16 KB full W2
    const int tid = threadIdx.x;
    const int v0 = blockIdx.x * 64;
    const int vend = (v0 + 64 < N) ? v0 + 64 : N;
    const int p = tid & 7;          // 8 lanes per row (128B fp16 row)

    // stage W2 early; loads retire under the gather phase
    for (int f = tid; f < 1024; f += 256)
        ((float4*)Wl)[f] = ((const float4*)W2)[f];

    const float4 bb0 = ((const float4*)b1)[2 * p];
    const float4 bb1 = ((const float4*)b1)[2 * p + 1];
    for (int v = v0 + (tid >> 3); v < vend; v += 32) {
        int pack = startcnt[v];
        int st = pack >> 7;           // 4-aligned
        int c = pack & 127;
        float dv = dinv[v];
        float a[8];
        h8_set(a, ((const int4*)(P + (size_t)v * 64))[p]);   // self: P' has dv
        for (int i = 0; i < c; i += 8) {
            int4 ua = *(const int4*)(csr + st + i);      // pad slots = 0, safe
            int4 ub = *(const int4*)(csr + st + i + 4);
            int4 m0 = ((const int4*)(P + (size_t)ua.x * 64))[p];
            int4 m1 = ((const int4*)(P + (size_t)ua.y * 64))[p];
            int4 m2 = ((const int4*)(P + (size_t)ua.z * 64))[p];
            int4 m3 = ((const int4*)(P + (size_t)ua.w * 64))[p];
            int4 m4 = ((const int4*)(P + (size_t)ub.x * 64))[p];
            int4 m5 = ((const int4*)(P + (size_t)ub.y * 64))[p];
            int4 m6 = ((const int4*)(P + (size_t)ub.z * 64))[p];
            int4 m7 = ((const int4*)(P + (size_t)ub.w * 64))[p];
            h8_acc(a, m0);
            if (i + 1 < c) h8_acc(a, m1);
            if (i + 2 < c) h8_acc(a, m2);
            if (i + 3 < c) h8_acc(a, m3);
            if (i + 4 < c) h8_acc(a, m4);
            if (i + 5 < c) h8_acc(a, m5);
            if (i + 6 < c) h8_acc(a, m6);
            if (i + 7 < c) h8_acc(a, m7);
        }
        float* hd = &hs[(v - v0) * 65 + p * 8];
        hd[0] = fmaxf(fmaf(a[0], dv, bb0.x), 0.f);
        hd[1] = fmaxf(fmaf(a[1], dv, bb0.y), 0.f);
        hd[2] = fmaxf(fmaf(a[2], dv, bb0.z), 0.f);
        hd[3] = fmaxf(fmaf(a[3], dv, bb0.w), 0.f);
        hd[4] = fmaxf(fmaf(a[4], dv, bb1.x), 0.f);
        hd[5] = fmaxf(fmaf(a[5], dv, bb1.y), 0.f);
        hd[6] = fmaxf(fmaf(a[6], dv, bb1.z), 0.f);
        hd[7] = fmaxf(fmaf(a[7], dv, bb1.w), 0.f);
    }
    __syncthreads();

    // Phase 2: Q'[v] = dinv * (hs @ W2); 2 rows x 8 cols per thread
    const int cg = tid & 7;
    const int n0 = tid >> 3;       // 0..31, 2 rows each
    float acc2[2][8];
#pragma unroll
    for (int r = 0; r < 2; r++)
#pragma unroll
        for (int j = 0; j < 8; j++) acc2[r][j] = 0.0f;
    for (int kk = 0; kk < 64; kk++) {     // RUNTIME loop (R6/R8 lesson)
        float x0 = hs[(n0 * 2 + 0) * 65 + kk];
        float x1 = hs[(n0 * 2 + 1) * 65 + kk];
        const float* wr = &Wl[kk * 64 + cg * 8];
        float4 w0 = *(const float4*)(wr + 0);
        float4 w1 = *(const float4*)(wr + 4);
        acc2[0][0] = fmaf(x0, w0.x, acc2[0][0]);
        acc2[0][1] = fmaf(x0, w0.y, acc2[0][1]);
        acc2[0][2] = fmaf(x0, w0.z, acc2[0][2]);
        acc2[0][3] = fmaf(x0, w0.w, acc2[0][3]);
        acc2[0][4] = fmaf(x0, w1.x, acc2[0][4]);
        acc2[0][5] = fmaf(x0, w1.y, acc2[0][5]);
        acc2[0][6] = fmaf(x0, w1.z, acc2[0][6]);
        acc2[0][7] = fmaf(x0, w1.w, acc2[0][7]);
        acc2[1][0] = fmaf(x1, w0.x, acc2[1][0]);
        acc2[1][1] = fmaf(x1, w0.y, acc2[1][1]);
        acc2[1][2] = fmaf(x1, w0.z, acc2[1][2]);
        acc2[1][3] = fmaf(x1, w0.w, acc2[1][3]);
        acc2[1][4] = fmaf(x1, w1.x, acc2[1][4]);
        acc2[1][5] = fmaf(x1, w1.y, acc2[1][5]);
        acc2[1][6] = fmaf(x1, w1.z, acc2[1][6]);
        acc2[1][7] = fmaf(x1, w1.w, acc2[1][7]);
    }
#pragma unroll
    for (int r = 0; r < 2; r++) {
        int node = v0 + n0 * 2 + r;
        if (node < N) {
            float d = dinv[node];
            __half2 hh[4];
            hh[0] = __floats2half2_rn(acc2[r][0] * d, acc2[r][1] * d);
            hh[1] = __floats2half2_rn(acc2[r][2] * d, acc2[r][3] * d);
            hh[2] = __floats2half2_rn(acc2[r][4] * d, acc2[r][5] * d);
            hh[3] = __floats2half2_rn(acc2[r][6] * d, acc2[r][7] * d);
            ((int4*)(Q + (size_t)node * 64))[cg] = *(int4*)hh;
        }
    }
}

// ---- layer-2 aggregate + attention pool + projection (Q' pre-scaled fp16) ----
#define GP_NODES 64
__global__ __launch_bounds__(256) void gather_pool_kernel(
    const __half* __restrict__ Q, const int* __restrict__ csr,
    const int* __restrict__ startcnt, const float* __restrict__ dinv,
    const float* __restrict__ bias, const int* __restrict__ batch,
    const float* __restrict__ attn_w, const float* __restrict__ attn_b,
    const float* __restrict__ mask_w, const float* __restrict__ mask_b,
    const float* __restrict__ out_w, float* __restrict__ out, int N) {
    __shared__ float pacc[2048];
    __shared__ int s_gmin, s_span;
    const int tid = threadIdx.x;
    const int v0 = blockIdx.x * GP_NODES;
    const int vend = (v0 + GP_NODES < N) ? v0 + GP_NODES : N;
    if (tid == 0) {
        int gmin = batch[v0];
        s_gmin = gmin;
        s_span = batch[vend - 1] - gmin + 1;
    }
    __syncthreads();
    const int gmin = s_gmin, span = s_span;
    for (int i = tid; i < span; i += 256) pacc[i] = 0.f;
    __syncthreads();

    const int p = tid & 7;          // 8 lanes per fp16 row
    const float4 wa0 = ((const float4*)attn_w)[2 * p], wa1 = ((const float4*)attn_w)[2 * p + 1];
    const float4 wm0 = ((const float4*)mask_w)[2 * p], wm1 = ((const float4*)mask_w)[2 * p + 1];
    const float4 wo0 = ((const float4*)out_w)[2 * p],  wo1 = ((const float4*)out_w)[2 * p + 1];
    const float4 bb0 = ((const float4*)bias)[2 * p],   bb1 = ((const float4*)bias)[2 * p + 1];
    const float ab = attn_b[0], mb = mask_b[0];

    for (int v = v0 + (tid >> 3); v < vend; v += 32) {
        int pack = startcnt[v];
        int st = pack >> 7;
        int c = pack & 127;
        float dv = dinv[v];
        float a[8];
        h8_set(a, ((const int4*)(Q + (size_t)v * 64))[p]);   // self (Q' = dv*Q)
        for (int i = 0; i < c; i += 8) {
            int4 ua = *(const int4*)(csr + st + i);
            int4 ub = *(const int4*)(csr + st + i + 4);
            int4 m0 = ((const int4*)(Q + (size_t)ua.x * 64))[p];
            int4 m1 = ((const int4*)(Q + (size_t)ua.y * 64))[p];
            int4 m2 = ((const int4*)(Q + (size_t)ua.z * 64))[p];
            int4 m3 = ((const int4*)(Q + (size_t)ua.w * 64))[p];
            int4 m4 = ((const int4*)(Q + (size_t)ub.x * 64))[p];
            int4 m5 = ((const int4*)(Q + (size_t)ub.y * 64))[p];
            int4 m6 = ((const int4*)(Q + (size_t)ub.z * 64))[p];
            int4 m7 = ((const int4*)(Q + (size_t)ub.w * 64))[p];
            h8_acc(a, m0);
            if (i + 1 < c) h8_acc(a, m1);
            if (i + 2 < c) h8_acc(a, m2);
            if (i + 3 < c) h8_acc(a, m3);
            if (i + 4 < c) h8_acc(a, m4);
            if (i + 5 < c) h8_acc(a, m5);
            if (i + 6 < c) h8_acc(a, m6);
            if (i + 7 < c) h8_acc(a, m7);
        }
        float h0 = fmaxf(fmaf(a[0], dv, bb0.x), 0.f);
        float h1v = fmaxf(fmaf(a[1], dv, bb0.y), 0.f);
        float h2v = fmaxf(fmaf(a[2], dv, bb0.z), 0.f);
        float h3 = fmaxf(fmaf(a[3], dv, bb0.w), 0.f);
        float h4 = fmaxf(fmaf(a[4], dv, bb1.x), 0.f);
        float h5 = fmaxf(fmaf(a[5], dv, bb1.y), 0.f);
        float h6 = fmaxf(fmaf(a[6], dv, bb1.z), 0.f);
        float h7 = fmaxf(fmaf(a[7], dv, bb1.w), 0.f);
        float pa = h0 * wa0.x + h1v * wa0.y + h2v * wa0.z + h3 * wa0.w
                 + h4 * wa1.x + h5 * wa1.y + h6 * wa1.z + h7 * wa1.w;
        float pm = h0 * wm0.x + h1v * wm0.y + h2v * wm0.z + h3 * wm0.w
                 + h4 * wm1.x + h5 * wm1.y + h6 * wm1.z + h7 * wm1.w;
        float po = h0 * wo0.x + h1v * wo0.y + h2v * wo0.z + h3 * wo0.w
                 + h4 * wo1.x + h5 * wo1.y + h6 * wo1.z + h7 * wo1.w;
#pragma unroll
        for (int off = 1; off < 8; off <<= 1) {   // 8-lane aligned groups
            pa += __shfl_xor(pa, off, 64);
            pm += __shfl_xor(pm, off, 64);
            po += __shfl_xor(po, off, 64);
        }
        if (p == 0) {
            float cc = (pa + ab) * (1.0f / (1.0f + expf(-(pm + mb)))) * po;
            atomicAdd(&pacc[batch[v] - gmin], cc);
        }
    }
    __syncthreads();
    for (int i = tid; i < span; i += 256) {
        float val = pacc[i];
        if (val != 0.f) atomicAdd(&out[gmin + i], val);
    }
}

extern "C" void kernel_launch(void* const* d_in, const int* in_sizes, int n_in,
                              void* d_out, int out_size, void* d_ws, size_t ws_size,
                              hipStream_t stream) {
    const float* x      = (const float*)d_in[0];
    const int*   edge   = (const int*)d_in[1];
    const int*   batch  = (const int*)d_in[2];
    const float* W1     = (const float*)d_in[3];
    const float* b1     = (const float*)d_in[4];
    const float* W2     = (const float*)d_in[5];
    const float* b2     = (const float*)d_in[6];
    const float* attn_w = (const float*)d_in[7];
    const float* attn_b = (const float*)d_in[8];
    const float* mask_w = (const float*)d_in[9];
    const float* mask_b = (const float*)d_in[10];
    const float* out_w  = (const float*)d_in[11];
    const float* out_b  = (const float*)d_in[12];
    float* out = (float*)d_out;

    const int N  = in_sizes[2];
    const int E  = in_sizes[1] / 2;
    const int K1 = in_sizes[0] / N;   // 128
    const int H  = in_sizes[4];       // 64
    const int G  = out_size;          // 2048
    const int* row = edge;            // edge_index[0] = sources
    const int* col = edge + E;        // edge_index[1] = targets

    const int NBUCK = (N + NB - 1) / NB;   // 1563

    // workspace: bcnt 1.6MB + gbuf 8MB + csr 8MB + startcnt/dinv 0.8MB
    //            + P/Q 2x12.8MB (fp16) ~= 44MB
    char* ws = (char*)d_ws;
    auto align256 = [](size_t s) { return (s + 255) / 256 * 256; };
    int*    bcnt     = (int*)ws;    ws += align256((size_t)NBUCK * SEG * 16 * 4);
    int*    gbuf     = (int*)ws;    ws += align256((size_t)NBUCK * SLOTS * 4);
    int*    csr      = (int*)ws;    ws += align256((size_t)NBUCK * SLOTS * 4);
    int*    startcnt = (int*)ws;    ws += align256((size_t)N * 4);
    float*  dinv     = (float*)ws;  ws += align256((size_t)N * 4);
    __half* P        = (__half*)ws; ws += align256((size_t)N * H * 2);
    __half* Q        = (__half*)ws;

    const int gblocks = (N + 127) / 128;

    hipMemsetAsync(bcnt, 0, (size_t)NBUCK * SEG * 16 * 4, stream);
    hipMemsetAsync(csr, 0, (size_t)NBUCK * SLOTS * 4, stream);  // 0-pad for int4 reads

    // fused: sharded per-edge binning (+out init) || P = x@W1 (fp16 out)
    gemm_bin_kernel<<<BIN_BLOCKS + gblocks, 256, 0, stream>>>(
        x, W1, P, N, K1, row, col, bcnt, gbuf, E, out, out_b, G);

    // per-bucket counting sort -> dense 4-aligned csr + startcnt + dinv
    // + pre-scale P' = dinv * P (bucket-local, coalesced, fp16)
    sort_kernel<<<NBUCK, 256, 0, stream>>>(bcnt, gbuf, csr, startcnt, dinv, P, N);

    // fused layer-1 aggregate (h1 -> LDS) + layer-2 GEMM: Q' = dinv*(h1@W2)
    gather_gemm_kernel<<<NBUCK, 256, 0, stream>>>(
        P, csr, startcnt, dinv, b1, W2, Q, N);

    // layer-2 aggregate + attention pool + projection
    gather_pool_kernel<<<NBUCK, 256, 0, stream>>>(
        Q, csr, startcnt, dinv, b2, batch, attn_w, attn_b, mask_w, mask_b, out_w, out, N);
}

// Round 8
// 230.511 us; speedup vs baseline: 1.1936x; 1.0376x over previous
//
#include <hip/hip_runtime.h>
#include <hip/hip_fp16.h>
#include <math.h>

// ---------------------------------------------------------------------------
// GCN: h1 = relu(Dinv (A+I) Dinv (x@W1) + b1); h2 = relu(Dinv (A+I) Dinv (h1@W2) + b2)
// score = (h2@aw+ab)*sigmoid(h2@mw+mb); out[g] = out_b + sum_v score*(h2@ow)
// R10 sharded bins + counting sort ->277. R12 gather_gemm fusion.
// R14: fp16 P/Q (fp32 accum) -> gathers -47us (238 total).
// BINNING SCOREBOARD (CLOSED, do not re-derive): 256-blk per-edge sharded =
//   58us LOCAL OPTIMUM. 512-blk = 71 (R18); x8-batched = 73 (R14);
//   64-blk two-pass = ~80 (R15). Wider/burstier/narrower all lose.
// R16: gather_gemm W2-from-global REGRESSED ~13us -> Wl-LDS form is right.
// R17: slice-major Q REGRESSED (line-granule overfetch 66MB). 128B full-row
//   = optimal gather granule; gather-layout experiments CLOSED.
// R19/R20 (this; R19 bench was an infra failure, resubmitted unchanged):
//   pure best-known recombination, no new levers: BIN_BLOCKS=256 binning
//   (58us measured) + R14 gather_gemm (Wl LDS, row-major fp16 Q) + R14
//   gather_pool. Expected ~225us. Next round profiles sort/gather_gemm/
//   gather_pool individually.
// ---------------------------------------------------------------------------

#define NB 64              // nodes per bucket (bucket = v >> 6)
#define SEG 16             // counter shards per bucket
#define CAPS 80            // slots per bucket-shard; mean 40, sd 6.3
#define SLOTS (SEG * CAPS) // 1280 slots per bucket
#define BIN_BLOCKS 256

__device__ __forceinline__ void h8_set(float* a, const int4 w) {
    const __half2* h = (const __half2*)&w;
    float2 t0 = __half22float2(h[0]);
    float2 t1 = __half22float2(h[1]);
    float2 t2 = __half22float2(h[2]);
    float2 t3 = __half22float2(h[3]);
    a[0] = t0.x; a[1] = t0.y; a[2] = t1.x; a[3] = t1.y;
    a[4] = t2.x; a[5] = t2.y; a[6] = t3.x; a[7] = t3.y;
}
__device__ __forceinline__ void h8_acc(float* a, const int4 w) {
    const __half2* h = (const __half2*)&w;
    float2 t0 = __half22float2(h[0]);
    float2 t1 = __half22float2(h[1]);
    float2 t2 = __half22float2(h[2]);
    float2 t3 = __half22float2(h[3]);
    a[0] += t0.x; a[1] += t0.y; a[2] += t1.x; a[3] += t1.y;
    a[4] += t2.x; a[5] += t2.y; a[6] += t3.x; a[7] += t3.y;
}

// ---- fused: blocks [0,BIN_BLOCKS) bin edges (+ init out); rest P = x@W1 ----
__global__ __launch_bounds__(256) void gemm_bin_kernel(
    const float* __restrict__ X, const float* __restrict__ W,
    __half* __restrict__ P, int N, int K,
    const int* __restrict__ row, const int* __restrict__ col,
    int* __restrict__ bcnt, int* __restrict__ gbuf, int E,
    float* __restrict__ out, const float* __restrict__ out_b, int G) {
    __shared__ float Wl[32 * 64];    // 8 KB
    __shared__ float xs[32 * 132];   // 16.9 KB TRANSPOSED x tile [k][node]

    if (blockIdx.x < BIN_BLOCKS) {
        // 256-blk per-edge sharded binning: the measured local optimum (58us)
        int seg = blockIdx.x & (SEG - 1);
        int t = blockIdx.x * 256 + threadIdx.x;
        if (t < G) out[t] = out_b[0];
        for (int e = t; e < E; e += BIN_BLOCKS * 256) {
            int c = col[e];
            int b = c >> 6;
            // counter padded to its own 64B line: ~40 atomics/line
            int pos = atomicAdd(&bcnt[(b * SEG + seg) * 16], 1);
            if (pos < CAPS) gbuf[b * SLOTS + seg * CAPS + pos] = row[e] | ((c & 63) << 17);
        }
        return;  // uniform per-block branch; never reaches a barrier
    }

    const int tid = threadIdx.x;
    const int cg = tid & 7;        // 8 col-groups x 8 cols
    const int ng = tid >> 3;       // 32 node-groups x 4 rows = 128 nodes
    const int node0 = (blockIdx.x - BIN_BLOCKS) * 128;

    float acc[4][8];
#pragma unroll
    for (int r = 0; r < 4; r++)
#pragma unroll
        for (int j = 0; j < 8; j++) acc[r][j] = 0.0f;

    for (int k0 = 0; k0 < K; k0 += 32) {   // runtime loop: keeps VGPR bounded
        const float4* Wg = (const float4*)(W + (size_t)k0 * 64);
#pragma unroll
        for (int f = tid; f < 512; f += 256) ((float4*)Wl)[f] = Wg[f];
        {
            int rrow = tid >> 1;
            int q0 = (tid & 1) * 16;
            int node = node0 + rrow;
            const float* Xr = X + (size_t)node * K + k0 + q0;
#pragma unroll
            for (int q = 0; q < 4; q++) {
                float4 v = make_float4(0.f, 0.f, 0.f, 0.f);
                if (node < N) v = *(const float4*)(Xr + 4 * q);
                int kb = q0 + 4 * q;           // transposed store: xs[k][node]
                xs[(kb + 0) * 132 + rrow] = v.x;
                xs[(kb + 1) * 132 + rrow] = v.y;
                xs[(kb + 2) * 132 + rrow] = v.z;
                xs[(kb + 3) * 132 + rrow] = v.w;
            }
        }
        __syncthreads();
#pragma unroll
        for (int kk = 0; kk < 32; kk++) {
            float4 xv = *(const float4*)&xs[kk * 132 + ng * 4];
            const float* wr = &Wl[kk * 64 + cg * 8];
            float4 w0 = *(const float4*)(wr + 0);
            float4 w1 = *(const float4*)(wr + 4);
#pragma unroll
            for (int r = 0; r < 4; r++) {
                float xr = (r == 0) ? xv.x : (r == 1) ? xv.y : (r == 2) ? xv.z : xv.w;
                acc[r][0] = fmaf(xr, w0.x, acc[r][0]);
                acc[r][1] = fmaf(xr, w0.y, acc[r][1]);
                acc[r][2] = fmaf(xr, w0.z, acc[r][2]);
                acc[r][3] = fmaf(xr, w0.w, acc[r][3]);
                acc[r][4] = fmaf(xr, w1.x, acc[r][4]);
                acc[r][5] = fmaf(xr, w1.y, acc[r][5]);
                acc[r][6] = fmaf(xr, w1.z, acc[r][6]);
                acc[r][7] = fmaf(xr, w1.w, acc[r][7]);
            }
        }
        __syncthreads();
    }

#pragma unroll
    for (int r = 0; r < 4; r++) {
        int node = node0 + ng * 4 + r;
        if (node < N) {
            __half2 hh[4];
            hh[0] = __floats2half2_rn(acc[r][0], acc[r][1]);
            hh[1] = __floats2half2_rn(acc[r][2], acc[r][3]);
            hh[2] = __floats2half2_rn(acc[r][4], acc[r][5]);
            hh[3] = __floats2half2_rn(acc[r][6], acc[r][7]);
            ((int4*)(P + (size_t)node * 64))[cg] = *(int4*)hh;
        }
    }
}

// ---- per-bucket LDS counting sort: gbuf segments -> dense node-ordered csr
//      (4-aligned per-node regions, pre-zeroed pad), writes dinv + packed
//      startcnt, then pre-scales P' = dinv * P (fp16 rows, coalesced) ----
__global__ __launch_bounds__(256) void sort_kernel(
    const int* __restrict__ bcnt, const int* __restrict__ gbuf,
    int* __restrict__ csr, int* __restrict__ startcnt,
    float* __restrict__ dinv, __half* __restrict__ P, int N) {
    __shared__ int scnt[SEG], segoff[SEG], s_tot;
    __shared__ int ebuf[SLOTS];     // 5 KB
    __shared__ int lcnt[NB], lcur[NB];
    __shared__ float sdinv[NB];
    const int tid = threadIdx.x;
    const int b = blockIdx.x;
    const int base = b * SLOTS;

    if (tid < SEG) {
        int c = bcnt[(b * SEG + tid) * 16];
        scnt[tid] = c < CAPS ? c : CAPS;
    }
    if (tid < NB) lcnt[tid] = 0;
    __syncthreads();
    if (tid == 0) {
        int o = 0;
        for (int s = 0; s < SEG; s++) { segoff[s] = o; o += scnt[s]; }
        s_tot = o;
    }
    __syncthreads();
    for (int idx = tid; idx < SLOTS; idx += 256) {
        int seg = idx / CAPS;
        int j = idx - seg * CAPS;
        if (j < scnt[seg]) {
            int w = gbuf[base + idx];
            ebuf[segoff[seg] + j] = w;
            atomicAdd(&lcnt[(w >> 17) & 63], 1);
        }
    }
    __syncthreads();
    if (tid < NB) {
        int cntv = lcnt[tid];
        int rnd = (cntv + 3) & ~3;          // 4-aligned region for int4 loads
        int val = rnd;
#pragma unroll
        for (int off = 1; off < 64; off <<= 1) {
            int n = __shfl_up(val, off, 64);
            if (tid >= off) val += n;
        }
        int st = val - rnd;
        lcur[tid] = st;
        float d = rsqrtf(1.0f + (float)cntv);
        sdinv[tid] = d;
        int v = b * NB + tid;
        if (v < N) {
            dinv[v] = d;
            int cc = cntv < 127 ? cntv : 127;
            startcnt[v] = ((base + st) << 7) | cc;   // base+st < 2M -> fits
        }
    }
    __syncthreads();
    int tot = s_tot;
    for (int idx = tid; idx < tot; idx += 256) {
        int w = ebuf[idx];
        int vl = (w >> 17) & 63;
        int pp = atomicAdd(&lcur[vl], 1);
        csr[base + pp] = w & 131071;
    }
    // pre-scale this bucket's fp16 P rows: P'[v] = dinv[v] * P[v]
    for (int idx = tid; idx < NB * 8; idx += 256) {   // 8x16B chunks per row
        int r = idx >> 3;
        int v = b * NB + r;
        if (v < N) {
            float d = sdinv[r];
            int4* pp = (int4*)(P + (size_t)v * 64) + (idx & 7);
            int4 t = *pp;
            __half2* hp = (__half2*)&t;
#pragma unroll
            for (int q = 0; q < 4; q++) {
                float2 f = __half22float2(hp[q]);
                hp[q] = __floats2half2_rn(f.x * d, f.y * d);
            }
            *pp = t;
        }
    }
}

// ---- fused layer-1 aggregate + layer-2 GEMM (R14-proven form) ----
// Phase 1: gather fp16 P' rows (8 lanes/row, int4/lane) -> fp32 -> h1 in LDS.
// Phase 2: Q' = dinv*(h1@W2) from LDS Wl; 2x8 register tile, RUNTIME kk-loop.
__global__ __launch_bounds__(256) void gather_gemm_kernel(
    const __half* __restrict__ P, const int* __restrict__ csr,
    const int* __restrict__ startcnt, const float* __restrict__ dinv,
    const float* __restrict__ b1, const float* __restrict__ W2,
    __half* __restrict__ Q, int N) {
    __shared__ float hs[64 * 65];   // 16.6 KB h1 tile
    __shared__ float Wl[64 * 64];   // 16 KB full W2
    const int tid = threadIdx.x;
    const int v0 = blockIdx.x * 64;
    const int vend = (v0 + 64 < N) ? v0 + 64 : N;
    const int p = tid & 7;          // 8 lanes per row (128B fp16 row)

    // stage W2 early; loads retire under the gather phase
    for (int f = tid; f < 1024; f += 256)
        ((float4*)Wl)[f] = ((const float4*)W2)[f];

    const float4 bb0 = ((const float4*)b1)[2 * p];
    const float4 bb1 = ((const float4*)b1)[2 * p + 1];
    for (int v = v0 + (tid >> 3); v < vend; v += 32) {
        int pack = startcnt[v];
        int st = pack >> 7;           // 4-aligned
        int c = pack & 127;
        float dv = dinv[v];
        float a[8];
        h8_set(a, ((const int4*)(P + (size_t)v * 64))[p]);   // self: P' has dv
        for (int i = 0; i < c; i += 8) {
            int4 ua = *(const int4*)(csr + st + i);      // pad slots = 0, safe
            int4 ub = *(const int4*)(csr + st + i + 4);
            int4 m0 = ((const int4*)(P + (size_t)ua.x * 64))[p];
            int4 m1 = ((const int4*)(P + (size_t)ua.y * 64))[p];
            int4 m2 = ((const int4*)(P + (size_t)ua.z * 64))[p];
            int4 m3 = ((const int4*)(P + (size_t)ua.w * 64))[p];
            int4 m4 = ((const int4*)(P + (size_t)ub.x * 64))[p];
            int4 m5 = ((const int4*)(P + (size_t)ub.y * 64))[p];
            int4 m6 = ((const int4*)(P + (size_t)ub.z * 64))[p];
            int4 m7 = ((const int4*)(P + (size_t)ub.w * 64))[p];
            h8_acc(a, m0);
            if (i + 1 < c) h8_acc(a, m1);
            if (i + 2 < c) h8_acc(a, m2);
            if (i + 3 < c) h8_acc(a, m3);
            if (i + 4 < c) h8_acc(a, m4);
            if (i + 5 < c) h8_acc(a, m5);
            if (i + 6 < c) h8_acc(a, m6);
            if (i + 7 < c) h8_acc(a, m7);
        }
        float* hd = &hs[(v - v0) * 65 + p * 8];
        hd[0] = fmaxf(fmaf(a[0], dv, bb0.x), 0.f);
        hd[1] = fmaxf(fmaf(a[1], dv, bb0.y), 0.f);
        hd[2] = fmaxf(fmaf(a[2], dv, bb0.z), 0.f);
        hd[3] = fmaxf(fmaf(a[3], dv, bb0.w), 0.f);
        hd[4] = fmaxf(fmaf(a[4], dv, bb1.x), 0.f);
        hd[5] = fmaxf(fmaf(a[5], dv, bb1.y), 0.f);
        hd[6] = fmaxf(fmaf(a[6], dv, bb1.z), 0.f);
        hd[7] = fmaxf(fmaf(a[7], dv, bb1.w), 0.f);
    }
    __syncthreads();

    // Phase 2: Q'[v] = dinv * (hs @ W2); 2 rows x 8 cols per thread
    const int cg = tid & 7;
    const int n0 = tid >> 3;       // 0..31, 2 rows each
    float acc2[2][8];
#pragma unroll
    for (int r = 0; r < 2; r++)
#pragma unroll
        for (int j = 0; j < 8; j++) acc2[r][j] = 0.0f;
    for (int kk = 0; kk < 64; kk++) {     // RUNTIME loop (R6/R8 lesson)
        float x0 = hs[(n0 * 2 + 0) * 65 + kk];
        float x1 = hs[(n0 * 2 + 1) * 65 + kk];
        const float* wr = &Wl[kk * 64 + cg * 8];
        float4 w0 = *(const float4*)(wr + 0);
        float4 w1 = *(const float4*)(wr + 4);
        acc2[0][0] = fmaf(x0, w0.x, acc2[0][0]);
        acc2[0][1] = fmaf(x0, w0.y, acc2[0][1]);
        acc2[0][2] = fmaf(x0, w0.z, acc2[0][2]);
        acc2[0][3] = fmaf(x0, w0.w, acc2[0][3]);
        acc2[0][4] = fmaf(x0, w1.x, acc2[0][4]);
        acc2[0][5] = fmaf(x0, w1.y, acc2[0][5]);
        acc2[0][6] = fmaf(x0, w1.z, acc2[0][6]);
        acc2[0][7] = fmaf(x0, w1.w, acc2[0][7]);
        acc2[1][0] = fmaf(x1, w0.x, acc2[1][0]);
        acc2[1][1] = fmaf(x1, w0.y, acc2[1][1]);
        acc2[1][2] = fmaf(x1, w0.z, acc2[1][2]);
        acc2[1][3] = fmaf(x1, w0.w, acc2[1][3]);
        acc2[1][4] = fmaf(x1, w1.x, acc2[1][4]);
        acc2[1][5] = fmaf(x1, w1.y, acc2[1][5]);
        acc2[1][6] = fmaf(x1, w1.z, acc2[1][6]);
        acc2[1][7] = fmaf(x1, w1.w, acc2[1][7]);
    }
#pragma unroll
    for (int r = 0; r < 2; r++) {
        int node = v0 + n0 * 2 + r;
        if (node < N) {
            float d = dinv[node];
            __half2 hh[4];
            hh[0] = __floats2half2_rn(acc2[r][0] * d, acc2[r][1] * d);
            hh[1] = __floats2half2_rn(acc2[r][2] * d, acc2[r][3] * d);
            hh[2] = __floats2half2_rn(acc2[r][4] * d, acc2[r][5] * d);
            hh[3] = __floats2half2_rn(acc2[r][6] * d, acc2[r][7] * d);
            ((int4*)(Q + (size_t)node * 64))[cg] = *(int4*)hh;
        }
    }
}

// ---- layer-2 aggregate + attention pool + projection (Q' pre-scaled fp16) ----
#define GP_NODES 64
__global__ __launch_bounds__(256) void gather_pool_kernel(
    const __half* __restrict__ Q, const int* __restrict__ csr,
    const int* __restrict__ startcnt, const float* __restrict__ dinv,
    const float* __restrict__ bias, const int* __restrict__ batch,
    const float* __restrict__ attn_w, const float* __restrict__ attn_b,
    const float* __restrict__ mask_w, const float* __restrict__ mask_b,
    const float* __restrict__ out_w, float* __restrict__ out, int N) {
    __shared__ float pacc[2048];
    __shared__ int s_gmin, s_span;
    const int tid = threadIdx.x;
    const int v0 = blockIdx.x * GP_NODES;
    const int vend = (v0 + GP_NODES < N) ? v0 + GP_NODES : N;
    if (tid == 0) {
        int gmin = batch[v0];
        s_gmin = gmin;
        s_span = batch[vend - 1] - gmin + 1;
    }
    __syncthreads();
    const int gmin = s_gmin, span = s_span;
    for (int i = tid; i < span; i += 256) pacc[i] = 0.f;
    __syncthreads();

    const int p = tid & 7;          // 8 lanes per fp16 row
    const float4 wa0 = ((const float4*)attn_w)[2 * p], wa1 = ((const float4*)attn_w)[2 * p + 1];
    const float4 wm0 = ((const float4*)mask_w)[2 * p], wm1 = ((const float4*)mask_w)[2 * p + 1];
    const float4 wo0 = ((const float4*)out_w)[2 * p],  wo1 = ((const float4*)out_w)[2 * p + 1];
    const float4 bb0 = ((const float4*)bias)[2 * p],   bb1 = ((const float4*)bias)[2 * p + 1];
    const float ab = attn_b[0], mb = mask_b[0];

    for (int v = v0 + (tid >> 3); v < vend; v += 32) {
        int pack = startcnt[v];
        int st = pack >> 7;
        int c = pack & 127;
        float dv = dinv[v];
        float a[8];
        h8_set(a, ((const int4*)(Q + (size_t)v * 64))[p]);   // self (Q' = dv*Q)
        for (int i = 0; i < c; i += 8) {
            int4 ua = *(const int4*)(csr + st + i);
            int4 ub = *(const int4*)(csr + st + i + 4);
            int4 m0 = ((const int4*)(Q + (size_t)ua.x * 64))[p];
            int4 m1 = ((const int4*)(Q + (size_t)ua.y * 64))[p];
            int4 m2 = ((const int4*)(Q + (size_t)ua.z * 64))[p];
            int4 m3 = ((const int4*)(Q + (size_t)ua.w * 64))[p];
            int4 m4 = ((const int4*)(Q + (size_t)ub.x * 64))[p];
            int4 m5 = ((const int4*)(Q + (size_t)ub.y * 64))[p];
            int4 m6 = ((const int4*)(Q + (size_t)ub.z * 64))[p];
            int4 m7 = ((const int4*)(Q + (size_t)ub.w * 64))[p];
            h8_acc(a, m0);
            if (i + 1 < c) h8_acc(a, m1);
            if (i + 2 < c) h8_acc(a, m2);
            if (i + 3 < c) h8_acc(a, m3);
            if (i + 4 < c) h8_acc(a, m4);
            if (i + 5 < c) h8_acc(a, m5);
            if (i + 6 < c) h8_acc(a, m6);
            if (i + 7 < c) h8_acc(a, m7);
        }
        float h0 = fmaxf(fmaf(a[0], dv, bb0.x), 0.f);
        float h1v = fmaxf(fmaf(a[1], dv, bb0.y), 0.f);
        float h2v = fmaxf(fmaf(a[2], dv, bb0.z), 0.f);
        float h3 = fmaxf(fmaf(a[3], dv, bb0.w), 0.f);
        float h4 = fmaxf(fmaf(a[4], dv, bb1.x), 0.f);
        float h5 = fmaxf(fmaf(a[5], dv, bb1.y), 0.f);
        float h6 = fmaxf(fmaf(a[6], dv, bb1.z), 0.f);
        float h7 = fmaxf(fmaf(a[7], dv, bb1.w), 0.f);
        float pa = h0 * wa0.x + h1v * wa0.y + h2v * wa0.z + h3 * wa0.w
                 + h4 * wa1.x + h5 * wa1.y + h6 * wa1.z + h7 * wa1.w;
        float pm = h0 * wm0.x + h1v * wm0.y + h2v * wm0.z + h3 * wm0.w
                 + h4 * wm1.x + h5 * wm1.y + h6 * wm1.z + h7 * wm1.w;
        float po = h0 * wo0.x + h1v * wo0.y + h2v * wo0.z + h3 * wo0.w
                 + h4 * wo1.x + h5 * wo1.y + h6 * wo1.z + h7 * wo1.w;
#pragma unroll
        for (int off = 1; off < 8; off <<= 1) {   // 8-lane aligned groups
            pa += __shfl_xor(pa, off, 64);
            pm += __shfl_xor(pm, off, 64);
            po += __shfl_xor(po, off, 64);
        }
        if (p == 0) {
            float cc = (pa + ab) * (1.0f / (1.0f + expf(-(pm + mb)))) * po;
            atomicAdd(&pacc[batch[v] - gmin], cc);
        }
    }
    __syncthreads();
    for (int i = tid; i < span; i += 256) {
        float val = pacc[i];
        if (val != 0.f) atomicAdd(&out[gmin + i], val);
    }
}

extern "C" void kernel_launch(void* const* d_in, const int* in_sizes, int n_in,
                              void* d_out, int out_size, void* d_ws, size_t ws_size,
                              hipStream_t stream) {
    const float* x      = (const float*)d_in[0];
    const int*   edge   = (const int*)d_in[1];
    const int*   batch  = (const int*)d_in[2];
    const float* W1     = (const float*)d_in[3];
    const float* b1     = (const float*)d_in[4];
    const float* W2     = (const float*)d_in[5];
    const float* b2     = (const float*)d_in[6];
    const float* attn_w = (const float*)d_in[7];
    const float* attn_b = (const float*)d_in[8];
    const float* mask_w = (const float*)d_in[9];
    const float* mask_b = (const float*)d_in[10];
    const float* out_w  = (const float*)d_in[11];
    const float* out_b  = (const float*)d_in[12];
    float* out = (float*)d_out;

    const int N  = in_sizes[2];
    const int E  = in_sizes[1] / 2;
    const int K1 = in_sizes[0] / N;   // 128
    const int H  = in_sizes[4];       // 64
    const int G  = out_size;          // 2048
    const int* row = edge;            // edge_index[0] = sources
    const int* col = edge + E;        // edge_index[1] = targets

    const int NBUCK = (N + NB - 1) / NB;   // 1563

    // workspace: bcnt 1.6MB + gbuf 8MB + csr 8MB + startcnt/dinv 0.8MB
    //            + P/Q 2x12.8MB (fp16) ~= 44MB
    char* ws = (char*)d_ws;
    auto align256 = [](size_t s) { return (s + 255) / 256 * 256; };
    int*    bcnt     = (int*)ws;    ws += align256((size_t)NBUCK * SEG * 16 * 4);
    int*    gbuf     = (int*)ws;    ws += align256((size_t)NBUCK * SLOTS * 4);
    int*    csr      = (int*)ws;    ws += align256((size_t)NBUCK * SLOTS * 4);
    int*    startcnt = (int*)ws;    ws += align256((size_t)N * 4);
    float*  dinv     = (float*)ws;  ws += align256((size_t)N * 4);
    __half* P        = (__half*)ws; ws += align256((size_t)N * H * 2);
    __half* Q        = (__half*)ws;

    const int gblocks = (N + 127) / 128;

    hipMemsetAsync(bcnt, 0, (size_t)NBUCK * SEG * 16 * 4, stream);
    hipMemsetAsync(csr, 0, (size_t)NBUCK * SLOTS * 4, stream);  // 0-pad for int4 reads

    // fused: sharded per-edge binning (+out init) || P = x@W1 (fp16 out)
    gemm_bin_kernel<<<BIN_BLOCKS + gblocks, 256, 0, stream>>>(
        x, W1, P, N, K1, row, col, bcnt, gbuf, E, out, out_b, G);

    // per-bucket counting sort -> dense 4-aligned csr + startcnt + dinv
    // + pre-scale P' = dinv * P (bucket-local, coalesced, fp16)
    sort_kernel<<<NBUCK, 256, 0, stream>>>(bcnt, gbuf, csr, startcnt, dinv, P, N);

    // fused layer-1 aggregate (h1 -> LDS) + layer-2 GEMM: Q' = dinv*(h1@W2)
    gather_gemm_kernel<<<NBUCK, 256, 0, stream>>>(
        P, csr, startcnt, dinv, b1, W2, Q, N);

    // layer-2 aggregate + attention pool + projection
    gather_pool_kernel<<<NBUCK, 256, 0, stream>>>(
        Q, csr, startcnt, dinv, b2, batch, attn_w, attn_b, mask_w, mask_b, out_w, out, N);
}

// Round 10
// 227.097 us; speedup vs baseline: 1.2116x; 1.0150x over previous
//
#include <hip/hip_runtime.h>
#include <hip/hip_fp16.h>
#include <math.h>

// ---------------------------------------------------------------------------
// GCN: h1 = relu(Dinv (A+I) Dinv (x@W1) + b1); h2 = relu(Dinv (A+I) Dinv (h1@W2) + b2)
// score = (h2@aw+ab)*sigmoid(h2@mw+mb); out[g] = out_b + sum_v score*(h2@ow)
// R10 sharded bins ->277. R12 gather_gemm fusion. R14 fp16 P/Q ->238.
// R19/20 best-known recombination -> 230.5.
// BINNING SCOREBOARD (CLOSED): 256-blk per-edge sharded = 58us = ~90% of the
//   ~19G/s coherent-RMW ceiling (1M atomics). AT ROOFLINE.
// R17: slice-major Q REGRESSED (line-granule overfetch). 128B row = optimal
//   gather granule. Layout experiments CLOSED.
// R21 CRASHED: dropping the csr memset left bucket-tail slots garbage; the
//   8-wide gather over-reads <=4 slots past the last node's padded region and
//   uses the value AS AN ADDRESS (dinv[u], P+u*64) even when predicated off
//   -> page fault. LESSON: every csr slot reachable by the 8-wide loop must
//   be a VALID node id; memset-zero is the guarantee. MEMSET IS LOAD-BEARING.
// R22 (this): R21(a) only -- drop sort's P-prescale (51MB streamed rw);
//   gather_gemm loads dinv[u] per neighbor (400KB, L2-resident; mul folds
//   into fmaf; single fp16 rounding of P). csr memset RESTORED.
// ---------------------------------------------------------------------------

#define NB 64              // nodes per bucket (bucket = v >> 6)
#define SEG 16             // counter shards per bucket
#define CAPS 80            // slots per bucket-shard; mean 40, sd 6.3
#define SLOTS (SEG * CAPS) // 1280 slots per bucket
#define BIN_BLOCKS 256

__device__ __forceinline__ void h8_set_s(float* a, const int4 w, float s) {
    const __half2* h = (const __half2*)&w;
    float2 t0 = __half22float2(h[0]);
    float2 t1 = __half22float2(h[1]);
    float2 t2 = __half22float2(h[2]);
    float2 t3 = __half22float2(h[3]);
    a[0] = s * t0.x; a[1] = s * t0.y; a[2] = s * t1.x; a[3] = s * t1.y;
    a[4] = s * t2.x; a[5] = s * t2.y; a[6] = s * t3.x; a[7] = s * t3.y;
}
__device__ __forceinline__ void h8_fma(float* a, const int4 w, float s) {
    const __half2* h = (const __half2*)&w;
    float2 t0 = __half22float2(h[0]);
    float2 t1 = __half22float2(h[1]);
    float2 t2 = __half22float2(h[2]);
    float2 t3 = __half22float2(h[3]);
    a[0] = fmaf(s, t0.x, a[0]); a[1] = fmaf(s, t0.y, a[1]);
    a[2] = fmaf(s, t1.x, a[2]); a[3] = fmaf(s, t1.y, a[3]);
    a[4] = fmaf(s, t2.x, a[4]); a[5] = fmaf(s, t2.y, a[5]);
    a[6] = fmaf(s, t3.x, a[6]); a[7] = fmaf(s, t3.y, a[7]);
}
__device__ __forceinline__ void h8_set(float* a, const int4 w) {
    const __half2* h = (const __half2*)&w;
    float2 t0 = __half22float2(h[0]);
    float2 t1 = __half22float2(h[1]);
    float2 t2 = __half22float2(h[2]);
    float2 t3 = __half22float2(h[3]);
    a[0] = t0.x; a[1] = t0.y; a[2] = t1.x; a[3] = t1.y;
    a[4] = t2.x; a[5] = t2.y; a[6] = t3.x; a[7] = t3.y;
}
__device__ __forceinline__ void h8_acc(float* a, const int4 w) {
    const __half2* h = (const __half2*)&w;
    float2 t0 = __half22float2(h[0]);
    float2 t1 = __half22float2(h[1]);
    float2 t2 = __half22float2(h[2]);
    float2 t3 = __half22float2(h[3]);
    a[0] += t0.x; a[1] += t0.y; a[2] += t1.x; a[3] += t1.y;
    a[4] += t2.x; a[5] += t2.y; a[6] += t3.x; a[7] += t3.y;
}

// ---- fused: blocks [0,BIN_BLOCKS) bin edges (+ init out); rest P = x@W1 ----
__global__ __launch_bounds__(256) void gemm_bin_kernel(
    const float* __restrict__ X, const float* __restrict__ W,
    __half* __restrict__ P, int N, int K,
    const int* __restrict__ row, const int* __restrict__ col,
    int* __restrict__ bcnt, int* __restrict__ gbuf, int E,
    float* __restrict__ out, const float* __restrict__ out_b, int G) {
    __shared__ float Wl[32 * 64];    // 8 KB
    __shared__ float xs[32 * 132];   // 16.9 KB TRANSPOSED x tile [k][node]

    if (blockIdx.x < BIN_BLOCKS) {
        // 256-blk per-edge sharded binning: measured ~90% of RMW ceiling
        int seg = blockIdx.x & (SEG - 1);
        int t = blockIdx.x * 256 + threadIdx.x;
        if (t < G) out[t] = out_b[0];
        for (int e = t; e < E; e += BIN_BLOCKS * 256) {
            int c = col[e];
            int b = c >> 6;
            // counter padded to its own 64B line: ~40 atomics/line
            int pos = atomicAdd(&bcnt[(b * SEG + seg) * 16], 1);
            if (pos < CAPS) gbuf[b * SLOTS + seg * CAPS + pos] = row[e] | ((c & 63) << 17);
        }
        return;  // uniform per-block branch; never reaches a barrier
    }

    const int tid = threadIdx.x;
    const int cg = tid & 7;        // 8 col-groups x 8 cols
    const int ng = tid >> 3;       // 32 node-groups x 4 rows = 128 nodes
    const int node0 = (blockIdx.x - BIN_BLOCKS) * 128;

    float acc[4][8];
#pragma unroll
    for (int r = 0; r < 4; r++)
#pragma unroll
        for (int j = 0; j < 8; j++) acc[r][j] = 0.0f;

    for (int k0 = 0; k0 < K; k0 += 32) {   // runtime loop: keeps VGPR bounded
        const float4* Wg = (const float4*)(W + (size_t)k0 * 64);
#pragma unroll
        for (int f = tid; f < 512; f += 256) ((float4*)Wl)[f] = Wg[f];
        {
            int rrow = tid >> 1;
            int q0 = (tid & 1) * 16;
            int node = node0 + rrow;
            const float* Xr = X + (size_t)node * K + k0 + q0;
#pragma unroll
            for (int q = 0; q < 4; q++) {
                float4 v = make_float4(0.f, 0.f, 0.f, 0.f);
                if (node < N) v = *(const float4*)(Xr + 4 * q);
                int kb = q0 + 4 * q;           // transposed store: xs[k][node]
                xs[(kb + 0) * 132 + rrow] = v.x;
                xs[(kb + 1) * 132 + rrow] = v.y;
                xs[(kb + 2) * 132 + rrow] = v.z;
                xs[(kb + 3) * 132 + rrow] = v.w;
            }
        }
        __syncthreads();
#pragma unroll
        for (int kk = 0; kk < 32; kk++) {
            float4 xv = *(const float4*)&xs[kk * 132 + ng * 4];
            const float* wr = &Wl[kk * 64 + cg * 8];
            float4 w0 = *(const float4*)(wr + 0);
            float4 w1 = *(const float4*)(wr + 4);
#pragma unroll
            for (int r = 0; r < 4; r++) {
                float xr = (r == 0) ? xv.x : (r == 1) ? xv.y : (r == 2) ? xv.z : xv.w;
                acc[r][0] = fmaf(xr, w0.x, acc[r][0]);
                acc[r][1] = fmaf(xr, w0.y, acc[r][1]);
                acc[r][2] = fmaf(xr, w0.z, acc[r][2]);
                acc[r][3] = fmaf(xr, w0.w, acc[r][3]);
                acc[r][4] = fmaf(xr, w1.x, acc[r][4]);
                acc[r][5] = fmaf(xr, w1.y, acc[r][5]);
                acc[r][6] = fmaf(xr, w1.z, acc[r][6]);
                acc[r][7] = fmaf(xr, w1.w, acc[r][7]);
            }
        }
        __syncthreads();
    }

#pragma unroll
    for (int r = 0; r < 4; r++) {
        int node = node0 + ng * 4 + r;
        if (node < N) {
            __half2 hh[4];
            hh[0] = __floats2half2_rn(acc[r][0], acc[r][1]);
            hh[1] = __floats2half2_rn(acc[r][2], acc[r][3]);
            hh[2] = __floats2half2_rn(acc[r][4], acc[r][5]);
            hh[3] = __floats2half2_rn(acc[r][6], acc[r][7]);
            ((int4*)(P + (size_t)node * 64))[cg] = *(int4*)hh;
        }
    }
}

// ---- per-bucket LDS counting sort: gbuf segments -> dense node-ordered csr
//      (4-aligned per-node regions; pads/tails pre-zeroed by memset),
//      writes dinv + packed startcnt. NO P-prescale (R22). ----
__global__ __launch_bounds__(256) void sort_kernel(
    const int* __restrict__ bcnt, const int* __restrict__ gbuf,
    int* __restrict__ csr, int* __restrict__ startcnt,
    float* __restrict__ dinv, int N) {
    __shared__ int scnt[SEG], segoff[SEG], s_tot;
    __shared__ int ebuf[SLOTS];     // 5 KB
    __shared__ int lcnt[NB], lcur[NB];
    const int tid = threadIdx.x;
    const int b = blockIdx.x;
    const int base = b * SLOTS;

    if (tid < SEG) {
        int c = bcnt[(b * SEG + tid) * 16];
        scnt[tid] = c < CAPS ? c : CAPS;
    }
    if (tid < NB) lcnt[tid] = 0;
    __syncthreads();
    if (tid == 0) {
        int o = 0;
        for (int s = 0; s < SEG; s++) { segoff[s] = o; o += scnt[s]; }
        s_tot = o;
    }
    __syncthreads();
    for (int idx = tid; idx < SLOTS; idx += 256) {
        int seg = idx / CAPS;
        int j = idx - seg * CAPS;
        if (j < scnt[seg]) {
            int w = gbuf[base + idx];
            ebuf[segoff[seg] + j] = w;
            atomicAdd(&lcnt[(w >> 17) & 63], 1);
        }
    }
    __syncthreads();
    if (tid < NB) {
        int cntv = lcnt[tid];
        int rnd = (cntv + 3) & ~3;          // 4-aligned region for int4 loads
        int val = rnd;
#pragma unroll
        for (int off = 1; off < 64; off <<= 1) {
            int n = __shfl_up(val, off, 64);
            if (tid >= off) val += n;
        }
        int st = val - rnd;
        lcur[tid] = st;
        int v = b * NB + tid;
        if (v < N) {
            dinv[v] = rsqrtf(1.0f + (float)cntv);
            int cc = cntv < 127 ? cntv : 127;
            startcnt[v] = ((base + st) << 7) | cc;   // base+st < 2M -> fits
        }
    }
    __syncthreads();
    int tot = s_tot;
    for (int idx = tid; idx < tot; idx += 256) {
        int w = ebuf[idx];
        int vl = (w >> 17) & 63;
        int pp = atomicAdd(&lcur[vl], 1);
        csr[base + pp] = w & 131071;
    }
}

// ---- fused layer-1 aggregate + layer-2 GEMM ----
// Phase 1: gather RAW fp16 P rows, scale by dinv[u] at read (dinv = 400KB,
// fully L2-resident), fp32 accum -> h1 in LDS. Phase 2: Q' = dinv*(h1@W2)
// from LDS Wl; 2x8 register tile, RUNTIME kk-loop; Q' stored pre-scaled.
__global__ __launch_bounds__(256) void gather_gemm_kernel(
    const __half* __restrict__ P, const int* __restrict__ csr,
    const int* __restrict__ startcnt, const float* __restrict__ dinv,
    const float* __restrict__ b1, const float* __restrict__ W2,
    __half* __restrict__ Q, int N) {
    __shared__ float hs[64 * 65];   // 16.6 KB h1 tile
    __shared__ float Wl[64 * 64];   // 16 KB full W2
    const int tid = threadIdx.x;
    const int v0 = blockIdx.x * 64;
    const int vend = (v0 + 64 < N) ? v0 + 64 : N;
    const int p = tid & 7;          // 8 lanes per row (128B fp16 row)

    // stage W2 early; loads retire under the gather phase
    for (int f = tid; f < 1024; f += 256)
        ((float4*)Wl)[f] = ((const float4*)W2)[f];

    const float4 bb0 = ((const float4*)b1)[2 * p];
    const float4 bb1 = ((const float4*)b1)[2 * p + 1];
    for (int v = v0 + (tid >> 3); v < vend; v += 32) {
        int pack = startcnt[v];
        int st = pack >> 7;           // 4-aligned
        int c = pack & 127;
        float dv = dinv[v];
        float a[8];
        h8_set_s(a, ((const int4*)(P + (size_t)v * 64))[p], dv);  // self: dv*P[v]
        for (int i = 0; i < c; i += 8) {
            int4 ua = *(const int4*)(csr + st + i);      // pad slots = 0 (memset)
            int4 ub = *(const int4*)(csr + st + i + 4);
            float du0 = dinv[ua.x], du1 = dinv[ua.y], du2 = dinv[ua.z], du3 = dinv[ua.w];
            float du4 = dinv[ub.x], du5 = dinv[ub.y], du6 = dinv[ub.z], du7 = dinv[ub.w];
            int4 m0 = ((const int4*)(P + (size_t)ua.x * 64))[p];
            int4 m1 = ((const int4*)(P + (size_t)ua.y * 64))[p];
            int4 m2 = ((const int4*)(P + (size_t)ua.z * 64))[p];
            int4 m3 = ((const int4*)(P + (size_t)ua.w * 64))[p];
            int4 m4 = ((const int4*)(P + (size_t)ub.x * 64))[p];
            int4 m5 = ((const int4*)(P + (size_t)ub.y * 64))[p];
            int4 m6 = ((const int4*)(P + (size_t)ub.z * 64))[p];
            int4 m7 = ((const int4*)(P + (size_t)ub.w * 64))[p];
            h8_fma(a, m0, du0);
            if (i + 1 < c) h8_fma(a, m1, du1);
            if (i + 2 < c) h8_fma(a, m2, du2);
            if (i + 3 < c) h8_fma(a, m3, du3);
            if (i + 4 < c) h8_fma(a, m4, du4);
            if (i + 5 < c) h8_fma(a, m5, du5);
            if (i + 6 < c) h8_fma(a, m6, du6);
            if (i + 7 < c) h8_fma(a, m7, du7);
        }
        float* hd = &hs[(v - v0) * 65 + p * 8];
        hd[0] = fmaxf(fmaf(a[0], dv, bb0.x), 0.f);
        hd[1] = fmaxf(fmaf(a[1], dv, bb0.y), 0.f);
        hd[2] = fmaxf(fmaf(a[2], dv, bb0.z), 0.f);
        hd[3] = fmaxf(fmaf(a[3], dv, bb0.w), 0.f);
        hd[4] = fmaxf(fmaf(a[4], dv, bb1.x), 0.f);
        hd[5] = fmaxf(fmaf(a[5], dv, bb1.y), 0.f);
        hd[6] = fmaxf(fmaf(a[6], dv, bb1.z), 0.f);
        hd[7] = fmaxf(fmaf(a[7], dv, bb1.w), 0.f);
    }
    __syncthreads();

    // Phase 2: Q'[v] = dinv * (hs @ W2); 2 rows x 8 cols per thread
    const int cg = tid & 7;
    const int n0 = tid >> 3;       // 0..31, 2 rows each
    float acc2[2][8];
#pragma unroll
    for (int r = 0; r < 2; r++)
#pragma unroll
        for (int j = 0; j < 8; j++) acc2[r][j] = 0.0f;
    for (int kk = 0; kk < 64; kk++) {     // RUNTIME loop (R6/R8 lesson)
        float x0 = hs[(n0 * 2 + 0) * 65 + kk];
        float x1 = hs[(n0 * 2 + 1) * 65 + kk];
        const float* wr = &Wl[kk * 64 + cg * 8];
        float4 w0 = *(const float4*)(wr + 0);
        float4 w1 = *(const float4*)(wr + 4);
        acc2[0][0] = fmaf(x0, w0.x, acc2[0][0]);
        acc2[0][1] = fmaf(x0, w0.y, acc2[0][1]);
        acc2[0][2] = fmaf(x0, w0.z, acc2[0][2]);
        acc2[0][3] = fmaf(x0, w0.w, acc2[0][3]);
        acc2[0][4] = fmaf(x0, w1.x, acc2[0][4]);
        acc2[0][5] = fmaf(x0, w1.y, acc2[0][5]);
        acc2[0][6] = fmaf(x0, w1.z, acc2[0][6]);
        acc2[0][7] = fmaf(x0, w1.w, acc2[0][7]);
        acc2[1][0] = fmaf(x1, w0.x, acc2[1][0]);
        acc2[1][1] = fmaf(x1, w0.y, acc2[1][1]);
        acc2[1][2] = fmaf(x1, w0.z, acc2[1][2]);
        acc2[1][3] = fmaf(x1, w0.w, acc2[1][3]);
        acc2[1][4] = fmaf(x1, w1.x, acc2[1][4]);
        acc2[1][5] = fmaf(x1, w1.y, acc2[1][5]);
        acc2[1][6] = fmaf(x1, w1.z, acc2[1][6]);
        acc2[1][7] = fmaf(x1, w1.w, acc2[1][7]);
    }
#pragma unroll
    for (int r = 0; r < 2; r++) {
        int node = v0 + n0 * 2 + r;
        if (node < N) {
            float d = dinv[node];
            __half2 hh[4];
            hh[0] = __floats2half2_rn(acc2[r][0] * d, acc2[r][1] * d);
            hh[1] = __floats2half2_rn(acc2[r][2] * d, acc2[r][3] * d);
            hh[2] = __floats2half2_rn(acc2[r][4] * d, acc2[r][5] * d);
            hh[3] = __floats2half2_rn(acc2[r][6] * d, acc2[r][7] * d);
            ((int4*)(Q + (size_t)node * 64))[cg] = *(int4*)hh;
        }
    }
}

// ---- layer-2 aggregate + attention pool + projection (Q' pre-scaled fp16) ----
#define GP_NODES 64
__global__ __launch_bounds__(256) void gather_pool_kernel(
    const __half* __restrict__ Q, const int* __restrict__ csr,
    const int* __restrict__ startcnt, const float* __restrict__ dinv,
    const float* __restrict__ bias, const int* __restrict__ batch,
    const float* __restrict__ attn_w, const float* __restrict__ attn_b,
    const float* __restrict__ mask_w, const float* __restrict__ mask_b,
    const float* __restrict__ out_w, float* __restrict__ out, int N) {
    __shared__ float pacc[2048];
    __shared__ int s_gmin, s_span;
    const int tid = threadIdx.x;
    const int v0 = blockIdx.x * GP_NODES;
    const int vend = (v0 + GP_NODES < N) ? v0 + GP_NODES : N;
    if (tid == 0) {
        int gmin = batch[v0];
        s_gmin = gmin;
        s_span = batch[vend - 1] - gmin + 1;
    }
    __syncthreads();
    const int gmin = s_gmin, span = s_span;
    for (int i = tid; i < span; i += 256) pacc[i] = 0.f;
    __syncthreads();

    const int p = tid & 7;          // 8 lanes per fp16 row
    const float4 wa0 = ((const float4*)attn_w)[2 * p], wa1 = ((const float4*)attn_w)[2 * p + 1];
    const float4 wm0 = ((const float4*)mask_w)[2 * p], wm1 = ((const float4*)mask_w)[2 * p + 1];
    const float4 wo0 = ((const float4*)out_w)[2 * p],  wo1 = ((const float4*)out_w)[2 * p + 1];
    const float4 bb0 = ((const float4*)bias)[2 * p],   bb1 = ((const float4*)bias)[2 * p + 1];
    const float ab = attn_b[0], mb = mask_b[0];

    for (int v = v0 + (tid >> 3); v < vend; v += 32) {
        int pack = startcnt[v];
        int st = pack >> 7;
        int c = pack & 127;
        float dv = dinv[v];
        float a[8];
        h8_set(a, ((const int4*)(Q + (size_t)v * 64))[p]);   // self (Q' = dv*Q)
        for (int i = 0; i < c; i += 8) {
            int4 ua = *(const int4*)(csr + st + i);
            int4 ub = *(const int4*)(csr + st + i + 4);
            int4 m0 = ((const int4*)(Q + (size_t)ua.x * 64))[p];
            int4 m1 = ((const int4*)(Q + (size_t)ua.y * 64))[p];
            int4 m2 = ((const int4*)(Q + (size_t)ua.z * 64))[p];
            int4 m3 = ((const int4*)(Q + (size_t)ua.w * 64))[p];
            int4 m4 = ((const int4*)(Q + (size_t)ub.x * 64))[p];
            int4 m5 = ((const int4*)(Q + (size_t)ub.y * 64))[p];
            int4 m6 = ((const int4*)(Q + (size_t)ub.z * 64))[p];
            int4 m7 = ((const int4*)(Q + (size_t)ub.w * 64))[p];
            h8_acc(a, m0);
            if (i + 1 < c) h8_acc(a, m1);
            if (i + 2 < c) h8_acc(a, m2);
            if (i + 3 < c) h8_acc(a, m3);
            if (i + 4 < c) h8_acc(a, m4);
            if (i + 5 < c) h8_acc(a, m5);
            if (i + 6 < c) h8_acc(a, m6);
            if (i + 7 < c) h8_acc(a, m7);
        }
        float h0 = fmaxf(fmaf(a[0], dv, bb0.x), 0.f);
        float h1v = fmaxf(fmaf(a[1], dv, bb0.y), 0.f);
        float h2v = fmaxf(fmaf(a[2], dv, bb0.z), 0.f);
        float h3 = fmaxf(fmaf(a[3], dv, bb0.w), 0.f);
        float h4 = fmaxf(fmaf(a[4], dv, bb1.x), 0.f);
        float h5 = fmaxf(fmaf(a[5], dv, bb1.y), 0.f);
        float h6 = fmaxf(fmaf(a[6], dv, bb1.z), 0.f);
        float h7 = fmaxf(fmaf(a[7], dv, bb1.w), 0.f);
        float pa = h0 * wa0.x + h1v * wa0.y + h2v * wa0.z + h3 * wa0.w
                 + h4 * wa1.x + h5 * wa1.y + h6 * wa1.z + h7 * wa1.w;
        float pm = h0 * wm0.x + h1v * wm0.y + h2v * wm0.z + h3 * wm0.w
                 + h4 * wm1.x + h5 * wm1.y + h6 * wm1.z + h7 * wm1.w;
        float po = h0 * wo0.x + h1v * wo0.y + h2v * wo0.z + h3 * wo0.w
                 + h4 * wo1.x + h5 * wo1.y + h6 * wo1.z + h7 * wo1.w;
#pragma unroll
        for (int off = 1; off < 8; off <<= 1) {   // 8-lane aligned groups
            pa += __shfl_xor(pa, off, 64);
            pm += __shfl_xor(pm, off, 64);
            po += __shfl_xor(po, off, 64);
        }
        if (p == 0) {
            float cc = (pa + ab) * (1.0f / (1.0f + expf(-(pm + mb)))) * po;
            atomicAdd(&pacc[batch[v] - gmin], cc);
        }
    }
    __syncthreads();
    for (int i = tid; i < span; i += 256) {
        float val = pacc[i];
        if (val != 0.f) atomicAdd(&out[gmin + i], val);
    }
}

extern "C" void kernel_launch(void* const* d_in, const int* in_sizes, int n_in,
                              void* d_out, int out_size, void* d_ws, size_t ws_size,
                              hipStream_t stream) {
    const float* x      = (const float*)d_in[0];
    const int*   edge   = (const int*)d_in[1];
    const int*   batch  = (const int*)d_in[2];
    const float* W1     = (const float*)d_in[3];
    const float* b1     = (const float*)d_in[4];
    const float* W2     = (const float*)d_in[5];
    const float* b2     = (const float*)d_in[6];
    const float* attn_w = (const float*)d_in[7];
    const float* attn_b = (const float*)d_in[8];
    const float* mask_w = (const float*)d_in[9];
    const float* mask_b = (const float*)d_in[10];
    const float* out_w  = (const float*)d_in[11];
    const float* out_b  = (const float*)d_in[12];
    float* out = (float*)d_out;

    const int N  = in_sizes[2];
    const int E  = in_sizes[1] / 2;
    const int K1 = in_sizes[0] / N;   // 128
    const int H  = in_sizes[4];       // 64
    const int G  = out_size;          // 2048
    const int* row = edge;            // edge_index[0] = sources
    const int* col = edge + E;        // edge_index[1] = targets

    const int NBUCK = (N + NB - 1) / NB;   // 1563

    // workspace: bcnt 1.6MB + gbuf 8MB + csr 8MB + startcnt/dinv 0.8MB
    //            + P/Q 2x12.8MB (fp16) ~= 44MB
    char* ws = (char*)d_ws;
    auto align256 = [](size_t s) { return (s + 255) / 256 * 256; };
    int*    bcnt     = (int*)ws;    ws += align256((size_t)NBUCK * SEG * 16 * 4);
    int*    gbuf     = (int*)ws;    ws += align256((size_t)NBUCK * SLOTS * 4);
    int*    csr      = (int*)ws;    ws += align256((size_t)NBUCK * SLOTS * 4);
    int*    startcnt = (int*)ws;    ws += align256((size_t)N * 4);
    float*  dinv     = (float*)ws;  ws += align256((size_t)N * 4);
    __half* P        = (__half*)ws; ws += align256((size_t)N * H * 2);
    __half* Q        = (__half*)ws;

    const int gblocks = (N + 127) / 128;

    hipMemsetAsync(bcnt, 0, (size_t)NBUCK * SEG * 16 * 4, stream);
    hipMemsetAsync(csr, 0, (size_t)NBUCK * SLOTS * 4, stream);  // LOAD-BEARING:
    // every csr slot reachable by the 8-wide gather must be a valid node id

    // fused: sharded per-edge binning (+out init) || P = x@W1 (fp16 out)
    gemm_bin_kernel<<<BIN_BLOCKS + gblocks, 256, 0, stream>>>(
        x, W1, P, N, K1, row, col, bcnt, gbuf, E, out, out_b, G);

    // per-bucket counting sort -> dense 4-aligned csr + startcnt + dinv
    sort_kernel<<<NBUCK, 256, 0, stream>>>(bcnt, gbuf, csr, startcnt, dinv, N);

    // fused layer-1 aggregate (dinv at read; h1 -> LDS) + layer-2 GEMM
    gather_gemm_kernel<<<NBUCK, 256, 0, stream>>>(
        P, csr, startcnt, dinv, b1, W2, Q, N);

    // layer-2 aggregate + attention pool + projection
    gather_pool_kernel<<<NBUCK, 256, 0, stream>>>(
        Q, csr, startcnt, dinv, b2, batch, attn_w, attn_b, mask_w, mask_b, out_w, out, N);
}

// Round 11
// 226.574 us; speedup vs baseline: 1.2144x; 1.0023x over previous
//
#include <hip/hip_runtime.h>
#include <hip/hip_fp16.h>
#include <math.h>

// ---------------------------------------------------------------------------
// GCN: h1 = relu(Dinv (A+I) Dinv (x@W1) + b1); h2 = relu(Dinv (A+I) Dinv (h1@W2) + b2)
// score = (h2@aw+ab)*sigmoid(h2@mw+mb); out[g] = out_b + sum_v score*(h2@ow)
// R10 sharded bins ->277. R12 gather_gemm fusion. R14 fp16 P/Q ->238.
// R19/20 recombination ->230.5. R22 drop P-prescale ->227.1.
// BINNING SCOREBOARD (CLOSED): 256-blk per-edge sharded = 58us = ~90% of the
//   ~19G/s coherent-RMW ceiling (1M atomics). AT ROOFLINE.
// R17: slice-major Q REGRESSED (line-granule overfetch). 128B row = optimal
//   gather granule. Layout experiments CLOSED.
// R21 CRASH LESSON: every csr slot reachable by the 8-wide gather must be a
//   VALID node id; the memset is LOAD-BEARING.
// R23 (this): 8-ALIGNED csr regions (rnd = ceil8(c), was ceil4). With 4-aligned
//   regions the 8-wide chunk loop over-read 4 slots of the NEXT node's region
//   for ~50% of nodes (c mod 8 in 1..4) = ~2 wasted RANDOM 128B rows/node
//   = ~20% extra random traffic (~25MB/layer, ~20us across both gathers).
//   8-aligned regions contain every chunk; overhang = memset-zero pads ->
//   row-0 broadcast reads (L1-hot), not random rows. Math bit-identical.
//   Capacity: E[tot_rnd8] ~= 890 < SLOTS=1280 (>7 sigma safe).
// ---------------------------------------------------------------------------

#define NB 64              // nodes per bucket (bucket = v >> 6)
#define SEG 16             // counter shards per bucket
#define CAPS 80            // slots per bucket-shard; mean 40, sd 6.3
#define SLOTS (SEG * CAPS) // 1280 slots per bucket
#define BIN_BLOCKS 256

__device__ __forceinline__ void h8_set_s(float* a, const int4 w, float s) {
    const __half2* h = (const __half2*)&w;
    float2 t0 = __half22float2(h[0]);
    float2 t1 = __half22float2(h[1]);
    float2 t2 = __half22float2(h[2]);
    float2 t3 = __half22float2(h[3]);
    a[0] = s * t0.x; a[1] = s * t0.y; a[2] = s * t1.x; a[3] = s * t1.y;
    a[4] = s * t2.x; a[5] = s * t2.y; a[6] = s * t3.x; a[7] = s * t3.y;
}
__device__ __forceinline__ void h8_fma(float* a, const int4 w, float s) {
    const __half2* h = (const __half2*)&w;
    float2 t0 = __half22float2(h[0]);
    float2 t1 = __half22float2(h[1]);
    float2 t2 = __half22float2(h[2]);
    float2 t3 = __half22float2(h[3]);
    a[0] = fmaf(s, t0.x, a[0]); a[1] = fmaf(s, t0.y, a[1]);
    a[2] = fmaf(s, t1.x, a[2]); a[3] = fmaf(s, t1.y, a[3]);
    a[4] = fmaf(s, t2.x, a[4]); a[5] = fmaf(s, t2.y, a[5]);
    a[6] = fmaf(s, t3.x, a[6]); a[7] = fmaf(s, t3.y, a[7]);
}
__device__ __forceinline__ void h8_set(float* a, const int4 w) {
    const __half2* h = (const __half2*)&w;
    float2 t0 = __half22float2(h[0]);
    float2 t1 = __half22float2(h[1]);
    float2 t2 = __half22float2(h[2]);
    float2 t3 = __half22float2(h[3]);
    a[0] = t0.x; a[1] = t0.y; a[2] = t1.x; a[3] = t1.y;
    a[4] = t2.x; a[5] = t2.y; a[6] = t3.x; a[7] = t3.y;
}
__device__ __forceinline__ void h8_acc(float* a, const int4 w) {
    const __half2* h = (const __half2*)&w;
    float2 t0 = __half22float2(h[0]);
    float2 t1 = __half22float2(h[1]);
    float2 t2 = __half22float2(h[2]);
    float2 t3 = __half22float2(h[3]);
    a[0] += t0.x; a[1] += t0.y; a[2] += t1.x; a[3] += t1.y;
    a[4] += t2.x; a[5] += t2.y; a[6] += t3.x; a[7] += t3.y;
}

// ---- fused: blocks [0,BIN_BLOCKS) bin edges (+ init out); rest P = x@W1 ----
__global__ __launch_bounds__(256) void gemm_bin_kernel(
    const float* __restrict__ X, const float* __restrict__ W,
    __half* __restrict__ P, int N, int K,
    const int* __restrict__ row, const int* __restrict__ col,
    int* __restrict__ bcnt, int* __restrict__ gbuf, int E,
    float* __restrict__ out, const float* __restrict__ out_b, int G) {
    __shared__ float Wl[32 * 64];    // 8 KB
    __shared__ float xs[32 * 132];   // 16.9 KB TRANSPOSED x tile [k][node]

    if (blockIdx.x < BIN_BLOCKS) {
        // 256-blk per-edge sharded binning: measured ~90% of RMW ceiling
        int seg = blockIdx.x & (SEG - 1);
        int t = blockIdx.x * 256 + threadIdx.x;
        if (t < G) out[t] = out_b[0];
        for (int e = t; e < E; e += BIN_BLOCKS * 256) {
            int c = col[e];
            int b = c >> 6;
            // counter padded to its own 64B line: ~40 atomics/line
            int pos = atomicAdd(&bcnt[(b * SEG + seg) * 16], 1);
            if (pos < CAPS) gbuf[b * SLOTS + seg * CAPS + pos] = row[e] | ((c & 63) << 17);
        }
        return;  // uniform per-block branch; never reaches a barrier
    }

    const int tid = threadIdx.x;
    const int cg = tid & 7;        // 8 col-groups x 8 cols
    const int ng = tid >> 3;       // 32 node-groups x 4 rows = 128 nodes
    const int node0 = (blockIdx.x - BIN_BLOCKS) * 128;

    float acc[4][8];
#pragma unroll
    for (int r = 0; r < 4; r++)
#pragma unroll
        for (int j = 0; j < 8; j++) acc[r][j] = 0.0f;

    for (int k0 = 0; k0 < K; k0 += 32) {   // runtime loop: keeps VGPR bounded
        const float4* Wg = (const float4*)(W + (size_t)k0 * 64);
#pragma unroll
        for (int f = tid; f < 512; f += 256) ((float4*)Wl)[f] = Wg[f];
        {
            int rrow = tid >> 1;
            int q0 = (tid & 1) * 16;
            int node = node0 + rrow;
            const float* Xr = X + (size_t)node * K + k0 + q0;
#pragma unroll
            for (int q = 0; q < 4; q++) {
                float4 v = make_float4(0.f, 0.f, 0.f, 0.f);
                if (node < N) v = *(const float4*)(Xr + 4 * q);
                int kb = q0 + 4 * q;           // transposed store: xs[k][node]
                xs[(kb + 0) * 132 + rrow] = v.x;
                xs[(kb + 1) * 132 + rrow] = v.y;
                xs[(kb + 2) * 132 + rrow] = v.z;
                xs[(kb + 3) * 132 + rrow] = v.w;
            }
        }
        __syncthreads();
#pragma unroll
        for (int kk = 0; kk < 32; kk++) {
            float4 xv = *(const float4*)&xs[kk * 132 + ng * 4];
            const float* wr = &Wl[kk * 64 + cg * 8];
            float4 w0 = *(const float4*)(wr + 0);
            float4 w1 = *(const float4*)(wr + 4);
#pragma unroll
            for (int r = 0; r < 4; r++) {
                float xr = (r == 0) ? xv.x : (r == 1) ? xv.y : (r == 2) ? xv.z : xv.w;
                acc[r][0] = fmaf(xr, w0.x, acc[r][0]);
                acc[r][1] = fmaf(xr, w0.y, acc[r][1]);
                acc[r][2] = fmaf(xr, w0.z, acc[r][2]);
                acc[r][3] = fmaf(xr, w0.w, acc[r][3]);
                acc[r][4] = fmaf(xr, w1.x, acc[r][4]);
                acc[r][5] = fmaf(xr, w1.y, acc[r][5]);
                acc[r][6] = fmaf(xr, w1.z, acc[r][6]);
                acc[r][7] = fmaf(xr, w1.w, acc[r][7]);
            }
        }
        __syncthreads();
    }

#pragma unroll
    for (int r = 0; r < 4; r++) {
        int node = node0 + ng * 4 + r;
        if (node < N) {
            __half2 hh[4];
            hh[0] = __floats2half2_rn(acc[r][0], acc[r][1]);
            hh[1] = __floats2half2_rn(acc[r][2], acc[r][3]);
            hh[2] = __floats2half2_rn(acc[r][4], acc[r][5]);
            hh[3] = __floats2half2_rn(acc[r][6], acc[r][7]);
            ((int4*)(P + (size_t)node * 64))[cg] = *(int4*)hh;
        }
    }
}

// ---- per-bucket LDS counting sort: gbuf segments -> dense node-ordered csr
//      (8-ALIGNED per-node regions, R23; pads pre-zeroed by memset),
//      writes dinv + packed startcnt. ----
__global__ __launch_bounds__(256) void sort_kernel(
    const int* __restrict__ bcnt, const int* __restrict__ gbuf,
    int* __restrict__ csr, int* __restrict__ startcnt,
    float* __restrict__ dinv, int N) {
    __shared__ int scnt[SEG], segoff[SEG], s_tot;
    __shared__ int ebuf[SLOTS];     // 5 KB
    __shared__ int lcnt[NB], lcur[NB];
    const int tid = threadIdx.x;
    const int b = blockIdx.x;
    const int base = b * SLOTS;

    if (tid < SEG) {
        int c = bcnt[(b * SEG + tid) * 16];
        scnt[tid] = c < CAPS ? c : CAPS;
    }
    if (tid < NB) lcnt[tid] = 0;
    __syncthreads();
    if (tid == 0) {
        int o = 0;
        for (int s = 0; s < SEG; s++) { segoff[s] = o; o += scnt[s]; }
        s_tot = o;
    }
    __syncthreads();
    for (int idx = tid; idx < SLOTS; idx += 256) {
        int seg = idx / CAPS;
        int j = idx - seg * CAPS;
        if (j < scnt[seg]) {
            int w = gbuf[base + idx];
            ebuf[segoff[seg] + j] = w;
            atomicAdd(&lcnt[(w >> 17) & 63], 1);
        }
    }
    __syncthreads();
    if (tid < NB) {
        int cntv = lcnt[tid];
        int rnd = (cntv + 7) & ~7;          // 8-ALIGNED region: 8-wide chunks
                                            // never touch the next node (R23)
        int val = rnd;
#pragma unroll
        for (int off = 1; off < 64; off <<= 1) {
            int n = __shfl_up(val, off, 64);
            if (tid >= off) val += n;
        }
        int st = val - rnd;
        lcur[tid] = st;
        int v = b * NB + tid;
        if (v < N) {
            dinv[v] = rsqrtf(1.0f + (float)cntv);
            int cc = cntv < 127 ? cntv : 127;
            startcnt[v] = ((base + st) << 7) | cc;   // base+st < 2M -> fits
        }
    }
    __syncthreads();
    int tot = s_tot;
    for (int idx = tid; idx < tot; idx += 256) {
        int w = ebuf[idx];
        int vl = (w >> 17) & 63;
        int pp = atomicAdd(&lcur[vl], 1);
        csr[base + pp] = w & 131071;
    }
}

// ---- fused layer-1 aggregate + layer-2 GEMM ----
// Phase 1: gather RAW fp16 P rows, scale by dinv[u] at read (dinv = 400KB,
// fully L2-resident), fp32 accum -> h1 in LDS. Phase 2: Q' = dinv*(h1@W2)
// from LDS Wl; 2x8 register tile, RUNTIME kk-loop; Q' stored pre-scaled.
__global__ __launch_bounds__(256) void gather_gemm_kernel(
    const __half* __restrict__ P, const int* __restrict__ csr,
    const int* __restrict__ startcnt, const float* __restrict__ dinv,
    const float* __restrict__ b1, const float* __restrict__ W2,
    __half* __restrict__ Q, int N) {
    __shared__ float hs[64 * 65];   // 16.6 KB h1 tile
    __shared__ float Wl[64 * 64];   // 16 KB full W2
    const int tid = threadIdx.x;
    const int v0 = blockIdx.x * 64;
    const int vend = (v0 + 64 < N) ? v0 + 64 : N;
    const int p = tid & 7;          // 8 lanes per row (128B fp16 row)

    // stage W2 early; loads retire under the gather phase
    for (int f = tid; f < 1024; f += 256)
        ((float4*)Wl)[f] = ((const float4*)W2)[f];

    const float4 bb0 = ((const float4*)b1)[2 * p];
    const float4 bb1 = ((const float4*)b1)[2 * p + 1];
    for (int v = v0 + (tid >> 3); v < vend; v += 32) {
        int pack = startcnt[v];
        int st = pack >> 7;           // 8-aligned
        int c = pack & 127;
        float dv = dinv[v];
        float a[8];
        h8_set_s(a, ((const int4*)(P + (size_t)v * 64))[p], dv);  // self: dv*P[v]
        for (int i = 0; i < c; i += 8) {
            int4 ua = *(const int4*)(csr + st + i);      // pad slots = 0 (memset)
            int4 ub = *(const int4*)(csr + st + i + 4);
            float du0 = dinv[ua.x], du1 = dinv[ua.y], du2 = dinv[ua.z], du3 = dinv[ua.w];
            float du4 = dinv[ub.x], du5 = dinv[ub.y], du6 = dinv[ub.z], du7 = dinv[ub.w];
            int4 m0 = ((const int4*)(P + (size_t)ua.x * 64))[p];
            int4 m1 = ((const int4*)(P + (size_t)ua.y * 64))[p];
            int4 m2 = ((const int4*)(P + (size_t)ua.z * 64))[p];
            int4 m3 = ((const int4*)(P + (size_t)ua.w * 64))[p];
            int4 m4 = ((const int4*)(P + (size_t)ub.x * 64))[p];
            int4 m5 = ((const int4*)(P + (size_t)ub.y * 64))[p];
            int4 m6 = ((const int4*)(P + (size_t)ub.z * 64))[p];
            int4 m7 = ((const int4*)(P + (size_t)ub.w * 64))[p];
            h8_fma(a, m0, du0);
            if (i + 1 < c) h8_fma(a, m1, du1);
            if (i + 2 < c) h8_fma(a, m2, du2);
            if (i + 3 < c) h8_fma(a, m3, du3);
            if (i + 4 < c) h8_fma(a, m4, du4);
            if (i + 5 < c) h8_fma(a, m5, du5);
            if (i + 6 < c) h8_fma(a, m6, du6);
            if (i + 7 < c) h8_fma(a, m7, du7);
        }
        float* hd = &hs[(v - v0) * 65 + p * 8];
        hd[0] = fmaxf(fmaf(a[0], dv, bb0.x), 0.f);
        hd[1] = fmaxf(fmaf(a[1], dv, bb0.y), 0.f);
        hd[2] = fmaxf(fmaf(a[2], dv, bb0.z), 0.f);
        hd[3] = fmaxf(fmaf(a[3], dv, bb0.w), 0.f);
        hd[4] = fmaxf(fmaf(a[4], dv, bb1.x), 0.f);
        hd[5] = fmaxf(fmaf(a[5], dv, bb1.y), 0.f);
        hd[6] = fmaxf(fmaf(a[6], dv, bb1.z), 0.f);
        hd[7] = fmaxf(fmaf(a[7], dv, bb1.w), 0.f);
    }
    __syncthreads();

    // Phase 2: Q'[v] = dinv * (hs @ W2); 2 rows x 8 cols per thread
    const int cg = tid & 7;
    const int n0 = tid >> 3;       // 0..31, 2 rows each
    float acc2[2][8];
#pragma unroll
    for (int r = 0; r < 2; r++)
#pragma unroll
        for (int j = 0; j < 8; j++) acc2[r][j] = 0.0f;
    for (int kk = 0; kk < 64; kk++) {     // RUNTIME loop (R6/R8 lesson)
        float x0 = hs[(n0 * 2 + 0) * 65 + kk];
        float x1 = hs[(n0 * 2 + 1) * 65 + kk];
        const float* wr = &Wl[kk * 64 + cg * 8];
        float4 w0 = *(const float4*)(wr + 0);
        float4 w1 = *(const float4*)(wr + 4);
        acc2[0][0] = fmaf(x0, w0.x, acc2[0][0]);
        acc2[0][1] = fmaf(x0, w0.y, acc2[0][1]);
        acc2[0][2] = fmaf(x0, w0.z, acc2[0][2]);
        acc2[0][3] = fmaf(x0, w0.w, acc2[0][3]);
        acc2[0][4] = fmaf(x0, w1.x, acc2[0][4]);
        acc2[0][5] = fmaf(x0, w1.y, acc2[0][5]);
        acc2[0][6] = fmaf(x0, w1.z, acc2[0][6]);
        acc2[0][7] = fmaf(x0, w1.w, acc2[0][7]);
        acc2[1][0] = fmaf(x1, w0.x, acc2[1][0]);
        acc2[1][1] = fmaf(x1, w0.y, acc2[1][1]);
        acc2[1][2] = fmaf(x1, w0.z, acc2[1][2]);
        acc2[1][3] = fmaf(x1, w0.w, acc2[1][3]);
        acc2[1][4] = fmaf(x1, w1.x, acc2[1][4]);
        acc2[1][5] = fmaf(x1, w1.y, acc2[1][5]);
        acc2[1][6] = fmaf(x1, w1.z, acc2[1][6]);
        acc2[1][7] = fmaf(x1, w1.w, acc2[1][7]);
    }
#pragma unroll
    for (int r = 0; r < 2; r++) {
        int node = v0 + n0 * 2 + r;
        if (node < N) {
            float d = dinv[node];
            __half2 hh[4];
            hh[0] = __floats2half2_rn(acc2[r][0] * d, acc2[r][1] * d);
            hh[1] = __floats2half2_rn(acc2[r][2] * d, acc2[r][3] * d);
            hh[2] = __floats2half2_rn(acc2[r][4] * d, acc2[r][5] * d);
            hh[3] = __floats2half2_rn(acc2[r][6] * d, acc2[r][7] * d);
            ((int4*)(Q + (size_t)node * 64))[cg] = *(int4*)hh;
        }
    }
}

// ---- layer-2 aggregate + attention pool + projection (Q' pre-scaled fp16) ----
#define GP_NODES 64
__global__ __launch_bounds__(256) void gather_pool_kernel(
    const __half* __restrict__ Q, const int* __restrict__ csr,
    const int* __restrict__ startcnt, const float* __restrict__ dinv,
    const float* __restrict__ bias, const int* __restrict__ batch,
    const float* __restrict__ attn_w, const float* __restrict__ attn_b,
    const float* __restrict__ mask_w, const float* __restrict__ mask_b,
    const float* __restrict__ out_w, float* __restrict__ out, int N) {
    __shared__ float pacc[2048];
    __shared__ int s_gmin, s_span;
    const int tid = threadIdx.x;
    const int v0 = blockIdx.x * GP_NODES;
    const int vend = (v0 + GP_NODES < N) ? v0 + GP_NODES : N;
    if (tid == 0) {
        int gmin = batch[v0];
        s_gmin = gmin;
        s_span = batch[vend - 1] - gmin + 1;
    }
    __syncthreads();
    const int gmin = s_gmin, span = s_span;
    for (int i = tid; i < span; i += 256) pacc[i] = 0.f;
    __syncthreads();

    const int p = tid & 7;          // 8 lanes per fp16 row
    const float4 wa0 = ((const float4*)attn_w)[2 * p], wa1 = ((const float4*)attn_w)[2 * p + 1];
    const float4 wm0 = ((const float4*)mask_w)[2 * p], wm1 = ((const float4*)mask_w)[2 * p + 1];
    const float4 wo0 = ((const float4*)out_w)[2 * p],  wo1 = ((const float4*)out_w)[2 * p + 1];
    const float4 bb0 = ((const float4*)bias)[2 * p],   bb1 = ((const float4*)bias)[2 * p + 1];
    const float ab = attn_b[0], mb = mask_b[0];

    for (int v = v0 + (tid >> 3); v < vend; v += 32) {
        int pack = startcnt[v];
        int st = pack >> 7;
        int c = pack & 127;
        float dv = dinv[v];
        float a[8];
        h8_set(a, ((const int4*)(Q + (size_t)v * 64))[p]);   // self (Q' = dv*Q)
        for (int i = 0; i < c; i += 8) {
            int4 ua = *(const int4*)(csr + st + i);
            int4 ub = *(const int4*)(csr + st + i + 4);
            int4 m0 = ((const int4*)(Q + (size_t)ua.x * 64))[p];
            int4 m1 = ((const int4*)(Q + (size_t)ua.y * 64))[p];
            int4 m2 = ((const int4*)(Q + (size_t)ua.z * 64))[p];
            int4 m3 = ((const int4*)(Q + (size_t)ua.w * 64))[p];
            int4 m4 = ((const int4*)(Q + (size_t)ub.x * 64))[p];
            int4 m5 = ((const int4*)(Q + (size_t)ub.y * 64))[p];
            int4 m6 = ((const int4*)(Q + (size_t)ub.z * 64))[p];
            int4 m7 = ((const int4*)(Q + (size_t)ub.w * 64))[p];
            h8_acc(a, m0);
            if (i + 1 < c) h8_acc(a, m1);
            if (i + 2 < c) h8_acc(a, m2);
            if (i + 3 < c) h8_acc(a, m3);
            if (i + 4 < c) h8_acc(a, m4);
            if (i + 5 < c) h8_acc(a, m5);
            if (i + 6 < c) h8_acc(a, m6);
            if (i + 7 < c) h8_acc(a, m7);
        }
        float h0 = fmaxf(fmaf(a[0], dv, bb0.x), 0.f);
        float h1v = fmaxf(fmaf(a[1], dv, bb0.y), 0.f);
        float h2v = fmaxf(fmaf(a[2], dv, bb0.z), 0.f);
        float h3 = fmaxf(fmaf(a[3], dv, bb0.w), 0.f);
        float h4 = fmaxf(fmaf(a[4], dv, bb1.x), 0.f);
        float h5 = fmaxf(fmaf(a[5], dv, bb1.y), 0.f);
        float h6 = fmaxf(fmaf(a[6], dv, bb1.z), 0.f);
        float h7 = fmaxf(fmaf(a[7], dv, bb1.w), 0.f);
        float pa = h0 * wa0.x + h1v * wa0.y + h2v * wa0.z + h3 * wa0.w
                 + h4 * wa1.x + h5 * wa1.y + h6 * wa1.z + h7 * wa1.w;
        float pm = h0 * wm0.x + h1v * wm0.y + h2v * wm0.z + h3 * wm0.w
                 + h4 * wm1.x + h5 * wm1.y + h6 * wm1.z + h7 * wm1.w;
        float po = h0 * wo0.x + h1v * wo0.y + h2v * wo0.z + h3 * wo0.w
                 + h4 * wo1.x + h5 * wo1.y + h6 * wo1.z + h7 * wo1.w;
#pragma unroll
        for (int off = 1; off < 8; off <<= 1) {   // 8-lane aligned groups
            pa += __shfl_xor(pa, off, 64);
            pm += __shfl_xor(pm, off, 64);
            po += __shfl_xor(po, off, 64);
        }
        if (p == 0) {
            float cc = (pa + ab) * (1.0f / (1.0f + expf(-(pm + mb)))) * po;
            atomicAdd(&pacc[batch[v] - gmin], cc);
        }
    }
    __syncthreads();
    for (int i = tid; i < span; i += 256) {
        float val = pacc[i];
        if (val != 0.f) atomicAdd(&out[gmin + i], val);
    }
}

extern "C" void kernel_launch(void* const* d_in, const int* in_sizes, int n_in,
                              void* d_out, int out_size, void* d_ws, size_t ws_size,
                              hipStream_t stream) {
    const float* x      = (const float*)d_in[0];
    const int*   edge   = (const int*)d_in[1];
    const int*   batch  = (const int*)d_in[2];
    const float* W1     = (const float*)d_in[3];
    const float* b1     = (const float*)d_in[4];
    const float* W2     = (const float*)d_in[5];
    const float* b2     = (const float*)d_in[6];
    const float* attn_w = (const float*)d_in[7];
    const float* attn_b = (const float*)d_in[8];
    const float* mask_w = (const float*)d_in[9];
    const float* mask_b = (const float*)d_in[10];
    const float* out_w  = (const float*)d_in[11];
    const float* out_b  = (const float*)d_in[12];
    float* out = (float*)d_out;

    const int N  = in_sizes[2];
    const int E  = in_sizes[1] / 2;
    const int K1 = in_sizes[0] / N;   // 128
    const int H  = in_sizes[4];       // 64
    const int G  = out_size;          // 2048
    const int* row = edge;            // edge_index[0] = sources
    const int* col = edge + E;        // edge_index[1] = targets

    const int NBUCK = (N + NB - 1) / NB;   // 1563

    // workspace: bcnt 1.6MB + gbuf 8MB + csr 8MB + startcnt/dinv 0.8MB
    //            + P/Q 2x12.8MB (fp16) ~= 44MB
    char* ws = (char*)d_ws;
    auto align256 = [](size_t s) { return (s + 255) / 256 * 256; };
    int*    bcnt     = (int*)ws;    ws += align256((size_t)NBUCK * SEG * 16 * 4);
    int*    gbuf     = (int*)ws;    ws += align256((size_t)NBUCK * SLOTS * 4);
    int*    csr      = (int*)ws;    ws += align256((size_t)NBUCK * SLOTS * 4);
    int*    startcnt = (int*)ws;    ws += align256((size_t)N * 4);
    float*  dinv     = (float*)ws;  ws += align256((size_t)N * 4);
    __half* P        = (__half*)ws; ws += align256((size_t)N * H * 2);
    __half* Q        = (__half*)ws;

    const int gblocks = (N + 127) / 128;

    hipMemsetAsync(bcnt, 0, (size_t)NBUCK * SEG * 16 * 4, stream);
    hipMemsetAsync(csr, 0, (size_t)NBUCK * SLOTS * 4, stream);  // LOAD-BEARING:
    // every csr slot reachable by the 8-wide gather must be a valid node id

    // fused: sharded per-edge binning (+out init) || P = x@W1 (fp16 out)
    gemm_bin_kernel<<<BIN_BLOCKS + gblocks, 256, 0, stream>>>(
        x, W1, P, N, K1, row, col, bcnt, gbuf, E, out, out_b, G);

    // per-bucket counting sort -> dense 8-aligned csr + startcnt + dinv
    sort_kernel<<<NBUCK, 256, 0, stream>>>(bcnt, gbuf, csr, startcnt, dinv, N);

    // fused layer-1 aggregate (dinv at read; h1 -> LDS) + layer-2 GEMM
    gather_gemm_kernel<<<NBUCK, 256, 0, stream>>>(
        P, csr, startcnt, dinv, b1, W2, Q, N);

    // layer-2 aggregate + attention pool + projection
    gather_pool_kernel<<<NBUCK, 256, 0, stream>>>(
        Q, csr, startcnt, dinv, b2, batch, attn_w, attn_b, mask_w, mask_b, out_w, out, N);
}